// Round 11
// baseline (319.208 us; speedup 1.0000x reference)
//
#include <hip/hip_runtime.h>

// MultiHashEncoding: 2-level dense grid trilinear interpolation.
// r10 evidence: LDS-binned main = 81us (VALU setup duplicated x4 per quad,
// 6.6M LDS conflict cycles, occ 27.7%), preprocessing = ~73us (4 passes).
// r11: (1) single-pass fixed-capacity binning (CAP=336 = mean+6.4sigma, with
// a correct overflow path; slots hold 4B orig index); (2) main kernel goes
// one-point-per-LANE so setup is computed once per point.
//
// Reference semantics (bit-exact corners): corner = floor(coords + OFFSET)
// with f32 add BEFORE floor; clip to [0,dim-1]; weight from CLIPPED corner.
//
// Staged-extent proof (r10, empirically validated): key uses the SAME f32
// products px*15/py*135/pz*240 as the coords, so floor(cx) in [2bx,2bx+1],
// floor(cy) in [8by,8by+7], floor(cz) in [8bz,8bz+7]; floor(c+1.0f) <=
// floor(c)+2 (binade). Extents: L0 4x10x10. L1: c1z=cz/2 exact -> z ext 6;
// x1b=bx ext 4; y1b=(544*by)/135 ext 8.

typedef float floatx4 __attribute__((ext_vector_type(4)));

#define KXB 8
#define KYB 17
#define KZB 31
#define NBINS (KXB * KYB * KZB)          // 4216
#define CAP 336

#define L0X 4
#define L0Y 10
#define L0Z 10
#define L0CELLS (L0X * L0Y * L0Z)        // 400
#define L1X 4
#define L1Y 8
#define L1Z 6
#define L1CELLS (L1X * L1Y * L1Z)        // 192
#define CSTR 20                          // 80B cell stride: bank-class spread

__device__ __forceinline__ int point_key(float px, float py, float pz) {
    int ix = (int)(px * 15.0f);  ix = min(max(ix, 0), 15);
    int iy = (int)(py * 135.0f); iy = min(max(iy, 0), 135);
    int iz = (int)(pz * 240.0f); iz = min(max(iz, 0), 240);
    return ((ix >> 1) * KYB + (iy >> 3)) * KZB + (iz >> 3);
}

__device__ __forceinline__ void load4pts(const float* __restrict__ pts, int i4,
                                         float px[4], float py[4], float pz[4]) {
    const floatx4* v = (const floatx4*)(pts + (size_t)i4 * 3);
    const floatx4 a = v[0], b = v[1], c = v[2];
    px[0] = a.x; py[0] = a.y; pz[0] = a.z;
    px[1] = a.w; py[1] = b.x; pz[1] = b.y;
    px[2] = b.z; py[2] = b.w; pz[2] = c.x;
    px[3] = c.y; py[3] = c.z; pz[3] = c.w;
}

// ---------------- single-pass binning ----------------
__global__ __launch_bounds__(256)
void k_bin(const float* __restrict__ pts, int n,
           unsigned* __restrict__ cnt, unsigned* __restrict__ ovfc,
           unsigned* __restrict__ slots, unsigned* __restrict__ ovf) {
    const int i4 = (blockIdx.x * blockDim.x + threadIdx.x) * 4;
    if (i4 >= n) return;
    if (i4 + 3 < n) {
        float px[4], py[4], pz[4];
        load4pts(pts, i4, px, py, pz);
#pragma unroll
        for (int j = 0; j < 4; ++j) {
            const int k = point_key(px[j], py[j], pz[j]);
            const unsigned pos = atomicAdd(&cnt[k], 1u);
            if (pos < CAP) slots[(size_t)k * CAP + pos] = (unsigned)(i4 + j);
            else           ovf[atomicAdd(ovfc, 1u)] = (unsigned)(i4 + j);
        }
    } else {
        for (int j = 0; j < 4 && i4 + j < n; ++j) {
            const size_t b = (size_t)(i4 + j) * 3;
            const int k = point_key(pts[b], pts[b+1], pts[b+2]);
            const unsigned pos = atomicAdd(&cnt[k], 1u);
            if (pos < CAP) slots[(size_t)k * CAP + pos] = (unsigned)(i4 + j);
            else           ovf[atomicAdd(ovfc, 1u)] = (unsigned)(i4 + j);
        }
    }
}

// ---------------- per-level corner setup (full point, dword offsets) -------
__device__ __forceinline__ void setup_lds(float cx, float cy, float cz,
                                          float tm1, float hm1, float wm1,
                                          int xb, int yb, int zb,
                                          int sx, int sy,
                                          int* __restrict__ off,
                                          float* __restrict__ w) {
    float gx[2] = { floorf(cx), floorf(cx + 1.0f) };
    float gy[2] = { floorf(cy), floorf(cy + 1.0f) };
    float gz[2] = { floorf(cz), floorf(cz + 1.0f) };
    float wx[2], wy[2], wz[2];
    int   xo[2], yo[2], zo[2];
#pragma unroll
    for (int b = 0; b < 2; ++b) {
        gx[b] = fminf(fmaxf(gx[b], 0.0f), tm1);
        gy[b] = fminf(fmaxf(gy[b], 0.0f), hm1);
        gz[b] = fminf(fmaxf(gz[b], 0.0f), wm1);
        wx[b] = 1.0f - fabsf(gx[b] - cx);
        wy[b] = 1.0f - fabsf(gy[b] - cy);
        wz[b] = 1.0f - fabsf(gz[b] - cz);
        xo[b] = ((int)gx[b] - xb) * sx;
        yo[b] = ((int)gy[b] - yb) * sy;
        zo[b] = ((int)gz[b] - zb) * CSTR;
    }
    float wyz[4];
    int   yzo[4];
#pragma unroll
    for (int j = 0; j < 2; ++j)
#pragma unroll
        for (int k = 0; k < 2; ++k) {
            wyz[2 * j + k] = wy[j] * wz[k];
            yzo[2 * j + k] = yo[j] + zo[k];
        }
#pragma unroll
    for (int c = 0; c < 8; ++c) {
        const int i = (c >> 2) & 1, jk = c & 3;
        w[c]   = wx[i] * wyz[jk];
        off[c] = xo[i] + yzo[jk];
    }
}

// ---------------- main: one block per bin, one point per LANE ----------------
__global__ __launch_bounds__(256)
void k_main_bins(const unsigned* __restrict__ slots,
                 const unsigned* __restrict__ cnt,
                 const float* __restrict__ pts,
                 const float* __restrict__ emb0,
                 const float* __restrict__ emb1,
                 float* __restrict__ out) {
    // bijective XCD swizzle: 4216 = 8 * 527 exactly
    const int bin = (blockIdx.x & 7) * 527 + (blockIdx.x >> 3);
    const unsigned nc = min(cnt[bin], (unsigned)CAP);
    if (nc == 0) return;            // uniform branch, before any barrier

    const int bz = bin % KZB;
    const int t1 = bin / KZB;
    const int by = t1 % KYB;
    const int bx = t1 / KYB;

    const int x0 = bx * 2, y0 = by * 8, z0 = bz * 8;
    const int x1b = bx, y1b = (544 * by) / 135, z1b = bz * 4;

    __shared__ float lds0[L0CELLS * CSTR];   // 32.0 KB
    __shared__ float lds1[L1CELLS * CSTR];   // 15.4 KB

    const int tid = threadIdx.x;
    for (int idx = tid; idx < L0CELLS * 4; idx += 256) {
        const int cell = idx >> 2, q = (idx & 3) * 4;
        const int lz = cell % L0Z;
        const int t = cell / L0Z;
        const int ly = t % L0Y, lx = t / L0Y;
        const int gx = min(x0 + lx, 15), gy = min(y0 + ly, 135), gz = min(z0 + lz, 240);
        const floatx4 v = *(const floatx4*)(emb0 + ((size_t)(gx * 136 + gy) * 241 + gz) * 16 + q);
        *(floatx4*)(lds0 + cell * CSTR + q) = v;
    }
    for (int idx = tid; idx < L1CELLS * 4; idx += 256) {
        const int cell = idx >> 2, q = (idx & 3) * 4;
        const int lz = cell % L1Z;
        const int t = cell / L1Z;
        const int ly = t % L1Y, lx = t / L1Y;
        const int gx = min(x1b + lx, 8), gy = min(y1b + ly, 68), gz = min(z1b + lz, 120);
        const floatx4 v = *(const floatx4*)(emb1 + ((size_t)(gx * 69 + gy) * 121 + gz) * 16 + q);
        *(floatx4*)(lds1 + cell * CSTR + q) = v;
    }
    __syncthreads();

    for (unsigned p = tid; p < nc; p += 256) {
        const int orig = (int)slots[(size_t)bin * CAP + p];
        const size_t pb = (size_t)orig * 3;
        const float px = pts[pb], py = pts[pb + 1], pz = pts[pb + 2];

        int   o0[8], o1[8];
        float w0[8], w1[8];
        setup_lds(px * 15.0f, py * 135.0f, pz * 240.0f, 15.0f, 135.0f, 240.0f,
                  x0, y0, z0, L0Y * L0Z * CSTR, L0Z * CSTR, o0, w0);
        setup_lds(px * 8.0f, py * 68.0f, pz * 120.0f, 8.0f, 68.0f, 120.0f,
                  x1b, y1b, z1b, L1Y * L1Z * CSTR, L1Z * CSTR, o1, w1);

        floatx4 A0[4] = {{0,0,0,0},{0,0,0,0},{0,0,0,0},{0,0,0,0}};
        floatx4 A1[4] = {{0,0,0,0},{0,0,0,0},{0,0,0,0},{0,0,0,0}};
#pragma unroll
        for (int c = 0; c < 8; ++c) {
            const float* cp = lds0 + o0[c];
#pragma unroll
            for (int q = 0; q < 4; ++q) A0[q] += w0[c] * *(const floatx4*)(cp + q * 4);
        }
#pragma unroll
        for (int c = 0; c < 8; ++c) {
            const float* cp = lds1 + o1[c];
#pragma unroll
            for (int q = 0; q < 4; ++q) A1[q] += w1[c] * *(const floatx4*)(cp + q * 4);
        }

        float* row = out + (size_t)orig * 32;
#pragma unroll
        for (int q = 0; q < 4; ++q)
            __builtin_nontemporal_store(A0[q], (floatx4*)(row + q * 4));
#pragma unroll
        for (int q = 0; q < 4; ++q)
            __builtin_nontemporal_store(A1[q], (floatx4*)(row + 16 + q * 4));
    }
}

// ---------------- global-gather setup (overflow + fallback) ----------------
__device__ __forceinline__ void setup_glb(float cx, float cy, float cz,
                                          float tm1, float hm1, float wm1,
                                          int sh, int sw, int d,
                                          int* __restrict__ off,
                                          float* __restrict__ w) {
    float gx[2] = { floorf(cx), floorf(cx + 1.0f) };
    float gy[2] = { floorf(cy), floorf(cy + 1.0f) };
    float gz[2] = { floorf(cz), floorf(cz + 1.0f) };
    float wx[2], wy[2], wz[2];
    int   xo[2], yo[2], zo[2];
#pragma unroll
    for (int b = 0; b < 2; ++b) {
        gx[b] = fminf(fmaxf(gx[b], 0.0f), tm1);
        gy[b] = fminf(fmaxf(gy[b], 0.0f), hm1);
        gz[b] = fminf(fmaxf(gz[b], 0.0f), wm1);
        wx[b] = 1.0f - fabsf(gx[b] - cx);
        wy[b] = 1.0f - fabsf(gy[b] - cy);
        wz[b] = 1.0f - fabsf(gz[b] - cz);
        xo[b] = (int)gx[b] * sh;
        yo[b] = (int)gy[b] * sw;
        zo[b] = (int)gz[b] * 16 + d;
    }
#pragma unroll
    for (int c = 0; c < 8; ++c) {
        const int i = (c >> 2) & 1, j = (c >> 1) & 1, k = c & 1;
        w[c]   = wx[i] * (wy[j] * wz[k]);
        off[c] = xo[i] + yo[j] + zo[k];
    }
}

// overflow: grid-stride over device-side count (empty in practice; outputs
// are bit-identical to the LDS path, so membership nondeterminism is safe)
__global__ __launch_bounds__(256)
void k_overflow(const unsigned* __restrict__ ovf, const unsigned* __restrict__ ovfc,
                const float* __restrict__ pts,
                const float* __restrict__ emb0, const float* __restrict__ emb1,
                float* __restrict__ out) {
    const unsigned total = *ovfc;
    for (unsigned i = blockIdx.x * 256 + threadIdx.x; i < total;
         i += gridDim.x * 256) {
        const int p = (int)ovf[i];
        const size_t b = (size_t)p * 3;
        const float px = pts[b], py = pts[b + 1], pz = pts[b + 2];
        int   o0[8], o1[8];
        float w0[8], w1[8];
        setup_glb(px * 15.0f, py * 135.0f, pz * 240.0f, 15.0f, 135.0f, 240.0f,
                  136 * 241 * 16, 241 * 16, 0, o0, w0);
        setup_glb(px * 8.0f, py * 68.0f, pz * 120.0f, 8.0f, 68.0f, 120.0f,
                  69 * 121 * 16, 121 * 16, 0, o1, w1);
        float* row = out + (size_t)p * 32;
#pragma unroll
        for (int q = 0; q < 4; ++q) {
            floatx4 a0 = {0,0,0,0}, a1 = {0,0,0,0};
#pragma unroll
            for (int c = 0; c < 8; ++c) {
                a0 += w0[c] * *(const floatx4*)(emb0 + o0[c] + q * 4);
                a1 += w1[c] * *(const floatx4*)(emb1 + o1[c] + q * 4);
            }
            __builtin_nontemporal_store(a0, (floatx4*)(row + q * 4));
            __builtin_nontemporal_store(a1, (floatx4*)(row + 16 + q * 4));
        }
    }
}

// fallback (ws too small): r6-style direct gathers, 4 lanes/point
__global__ __launch_bounds__(256)
void k_main_plain(const float* __restrict__ pts,
                  const float* __restrict__ emb0,
                  const float* __restrict__ emb1,
                  float* __restrict__ out, int n) {
    const int g = blockIdx.x * blockDim.x + threadIdx.x;
    const int p = g >> 2;
    const int d = (g & 3) * 4;
    if (p >= n) return;
    const size_t b = (size_t)p * 3;
    const float px = pts[b], py = pts[b + 1], pz = pts[b + 2];
    int   o0[8], o1[8];
    float w0[8], w1[8];
    setup_glb(px * 15.0f, py * 135.0f, pz * 240.0f, 15.0f, 135.0f, 240.0f,
              136 * 241 * 16, 241 * 16, d, o0, w0);
    setup_glb(px * 8.0f, py * 68.0f, pz * 120.0f, 8.0f, 68.0f, 120.0f,
              69 * 121 * 16, 121 * 16, d, o1, w1);
    floatx4 a0 = {0,0,0,0}, a1 = {0,0,0,0};
#pragma unroll
    for (int c = 0; c < 8; ++c) a0 += w0[c] * *(const floatx4*)(emb0 + o0[c]);
#pragma unroll
    for (int c = 0; c < 8; ++c) a1 += w1[c] * *(const floatx4*)(emb1 + o1[c]);
    float* row = out + (size_t)p * 32 + d;
    __builtin_nontemporal_store(a0, (floatx4*)row);
    __builtin_nontemporal_store(a1, (floatx4*)(row + 16));
}

extern "C" void kernel_launch(void* const* d_in, const int* in_sizes, int n_in,
                              void* d_out, int out_size, void* d_ws, size_t ws_size,
                              hipStream_t stream) {
    const float* pts  = (const float*)d_in[0];
    const float* emb0 = (const float*)d_in[1];
    const float* emb1 = (const float*)d_in[2];
    float* out = (float*)d_out;
    const int n = in_sizes[0] / 3;

    const int block = 256;
    const int n4      = (n + 3) / 4;
    const int grid_p4 = (n4 + block - 1) / block;
    const int grid_4l = (int)(((long long)n * 4 + block - 1) / block);

    // workspace layout: cnt | ovfc | slots | ovf
    const size_t off_cnt   = 0;
    const size_t off_ovfc  = (size_t)NBINS * 4;
    const size_t off_slots = ((off_ovfc + 4 + 31) & ~(size_t)31);
    const size_t off_ovf   = off_slots + (size_t)NBINS * CAP * 4;
    const size_t need      = off_ovf + (size_t)n * 4;

    if (ws_size < need) {
        k_main_plain<<<grid_4l, block, 0, stream>>>(pts, emb0, emb1, out, n);
        return;
    }

    char* ws = (char*)d_ws;
    unsigned* cnt   = (unsigned*)(ws + off_cnt);
    unsigned* ovfc  = (unsigned*)(ws + off_ovfc);
    unsigned* slots = (unsigned*)(ws + off_slots);
    unsigned* ovf   = (unsigned*)(ws + off_ovf);

    hipMemsetAsync(cnt, 0, off_ovfc + 4, stream);   // cnt + ovfc in one shot
    k_bin<<<grid_p4, block, 0, stream>>>(pts, n, cnt, ovfc, slots, ovf);
    k_main_bins<<<NBINS, block, 0, stream>>>(slots, cnt, pts, emb0, emb1, out);
    k_overflow<<<64, block, 0, stream>>>(ovf, ovfc, pts, emb0, emb1, out);
}

// Round 12
// 151.144 us; speedup vs baseline: 2.1119x; 2.1119x over previous
//
#include <hip/hip_runtime.h>

// MultiHashEncoding: 2-level dense grid trilinear interpolation.
// r11 post-mortem: one-point-per-lane main wrote 64 scattered 16B NT stores
// per instr -> partial-line HBM RMW (WRITE 126->420MB, main 81->250us).
// r12: restore r10's QUAD-per-point main (full-line writes, proven 81us),
// keep r11's single-pass binning (4B idx slots, CAP=336, overflow path);
// quad reads pts[idx] via broadcast loads (12MB, L2-resident).
//
// Reference semantics (bit-exact corners): corner = floor(coords + OFFSET)
// with f32 add BEFORE floor; clip to [0,dim-1]; weight from CLIPPED corner.
//
// Staged-extent proof (r10, validated): key uses the SAME f32 products
// px*15/py*135/pz*240 as the coords, so floor(cx) in [2bx,2bx+1], floor(cy)
// in [8by,8by+7], floor(cz) in [8bz,8bz+7]; floor(c+1.0f) <= floor(c)+2
// (binade). Extents: L0 4x10x10. L1: c1z=cz/2 exact -> z ext 6; x1b=bx
// ext 4; y1b=(544*by)/135 ext 8.

typedef float floatx4 __attribute__((ext_vector_type(4)));

#define KXB 8
#define KYB 17
#define KZB 31
#define NBINS (KXB * KYB * KZB)          // 4216
#define CAP 336

#define L0X 4
#define L0Y 10
#define L0Z 10
#define L0CELLS (L0X * L0Y * L0Z)        // 400
#define L1X 4
#define L1Y 8
#define L1Z 6
#define L1CELLS (L1X * L1Y * L1Z)        // 192
#define CSTR 20                          // 80B cell stride: bank-class spread

__device__ __forceinline__ int point_key(float px, float py, float pz) {
    int ix = (int)(px * 15.0f);  ix = min(max(ix, 0), 15);
    int iy = (int)(py * 135.0f); iy = min(max(iy, 0), 135);
    int iz = (int)(pz * 240.0f); iz = min(max(iz, 0), 240);
    return ((ix >> 1) * KYB + (iy >> 3)) * KZB + (iz >> 3);
}

__device__ __forceinline__ void load4pts(const float* __restrict__ pts, int i4,
                                         float px[4], float py[4], float pz[4]) {
    const floatx4* v = (const floatx4*)(pts + (size_t)i4 * 3);
    const floatx4 a = v[0], b = v[1], c = v[2];
    px[0] = a.x; py[0] = a.y; pz[0] = a.z;
    px[1] = a.w; py[1] = b.x; pz[1] = b.y;
    px[2] = b.z; py[2] = b.w; pz[2] = c.x;
    px[3] = c.y; py[3] = c.z; pz[3] = c.w;
}

// ---------------- single-pass binning ----------------
__global__ __launch_bounds__(256)
void k_bin(const float* __restrict__ pts, int n,
           unsigned* __restrict__ cnt, unsigned* __restrict__ ovfc,
           unsigned* __restrict__ slots, unsigned* __restrict__ ovf) {
    const int i4 = (blockIdx.x * blockDim.x + threadIdx.x) * 4;
    if (i4 >= n) return;
    if (i4 + 3 < n) {
        float px[4], py[4], pz[4];
        load4pts(pts, i4, px, py, pz);
        int k[4];
#pragma unroll
        for (int j = 0; j < 4; ++j) k[j] = point_key(px[j], py[j], pz[j]);
        unsigned pos[4];
#pragma unroll
        for (int j = 0; j < 4; ++j) pos[j] = atomicAdd(&cnt[k[j]], 1u);
#pragma unroll
        for (int j = 0; j < 4; ++j) {
            if (pos[j] < CAP) slots[(size_t)k[j] * CAP + pos[j]] = (unsigned)(i4 + j);
            else              ovf[atomicAdd(ovfc, 1u)] = (unsigned)(i4 + j);
        }
    } else {
        for (int j = 0; j < 4 && i4 + j < n; ++j) {
            const size_t b = (size_t)(i4 + j) * 3;
            const int k = point_key(pts[b], pts[b+1], pts[b+2]);
            const unsigned pos = atomicAdd(&cnt[k], 1u);
            if (pos < CAP) slots[(size_t)k * CAP + pos] = (unsigned)(i4 + j);
            else           ovf[atomicAdd(ovfc, 1u)] = (unsigned)(i4 + j);
        }
    }
}

// ------- per-level corner setup (LDS dword offsets, d folded into z) -------
__device__ __forceinline__ void setup_lds(float cx, float cy, float cz,
                                          float tm1, float hm1, float wm1,
                                          int xb, int yb, int zb,
                                          int sx, int sy, int d,
                                          int* __restrict__ off,
                                          float* __restrict__ w) {
    float gx[2] = { floorf(cx), floorf(cx + 1.0f) };
    float gy[2] = { floorf(cy), floorf(cy + 1.0f) };
    float gz[2] = { floorf(cz), floorf(cz + 1.0f) };
    float wx[2], wy[2], wz[2];
    int   xo[2], yo[2], zo[2];
#pragma unroll
    for (int b = 0; b < 2; ++b) {
        gx[b] = fminf(fmaxf(gx[b], 0.0f), tm1);
        gy[b] = fminf(fmaxf(gy[b], 0.0f), hm1);
        gz[b] = fminf(fmaxf(gz[b], 0.0f), wm1);
        wx[b] = 1.0f - fabsf(gx[b] - cx);
        wy[b] = 1.0f - fabsf(gy[b] - cy);
        wz[b] = 1.0f - fabsf(gz[b] - cz);
        xo[b] = ((int)gx[b] - xb) * sx;
        yo[b] = ((int)gy[b] - yb) * sy;
        zo[b] = ((int)gz[b] - zb) * CSTR + d;
    }
    float wyz[4];
    int   yzo[4];
#pragma unroll
    for (int j = 0; j < 2; ++j)
#pragma unroll
        for (int k = 0; k < 2; ++k) {
            wyz[2 * j + k] = wy[j] * wz[k];
            yzo[2 * j + k] = yo[j] + zo[k];
        }
#pragma unroll
    for (int c = 0; c < 8; ++c) {
        const int i = (c >> 2) & 1, jk = c & 3;
        w[c]   = wx[i] * wyz[jk];
        off[c] = xo[i] + yzo[jk];
    }
}

// ---------------- main: one block per bin, QUAD per point ----------------
__global__ __launch_bounds__(256)
void k_main_bins(const unsigned* __restrict__ slots,
                 const unsigned* __restrict__ cnt,
                 const float* __restrict__ pts,
                 const float* __restrict__ emb0,
                 const float* __restrict__ emb1,
                 float* __restrict__ out) {
    // bijective XCD swizzle: 4216 = 8 * 527 exactly
    const int bin = (blockIdx.x & 7) * 527 + (blockIdx.x >> 3);
    const unsigned nc = min(cnt[bin], (unsigned)CAP);
    if (nc == 0) return;            // uniform branch, before any barrier

    const int bz = bin % KZB;
    const int t1 = bin / KZB;
    const int by = t1 % KYB;
    const int bx = t1 / KYB;

    const int x0 = bx * 2, y0 = by * 8, z0 = bz * 8;
    const int x1b = bx, y1b = (544 * by) / 135, z1b = bz * 4;

    __shared__ float lds0[L0CELLS * CSTR];   // 32.0 KB
    __shared__ float lds1[L1CELLS * CSTR];   // 15.4 KB

    const int tid = threadIdx.x;
    for (int idx = tid; idx < L0CELLS * 4; idx += 256) {
        const int cell = idx >> 2, q = (idx & 3) * 4;
        const int lz = cell % L0Z;
        const int t = cell / L0Z;
        const int ly = t % L0Y, lx = t / L0Y;
        const int gx = min(x0 + lx, 15), gy = min(y0 + ly, 135), gz = min(z0 + lz, 240);
        const floatx4 v = *(const floatx4*)(emb0 + ((size_t)(gx * 136 + gy) * 241 + gz) * 16 + q);
        *(floatx4*)(lds0 + cell * CSTR + q) = v;
    }
    for (int idx = tid; idx < L1CELLS * 4; idx += 256) {
        const int cell = idx >> 2, q = (idx & 3) * 4;
        const int lz = cell % L1Z;
        const int t = cell / L1Z;
        const int ly = t % L1Y, lx = t / L1Y;
        const int gx = min(x1b + lx, 8), gy = min(y1b + ly, 68), gz = min(z1b + lz, 120);
        const floatx4 v = *(const floatx4*)(emb1 + ((size_t)(gx * 69 + gy) * 121 + gz) * 16 + q);
        *(floatx4*)(lds1 + cell * CSTR + q) = v;
    }
    __syncthreads();

    const int quad = tid >> 2;          // 64 quads/block
    const int d = (tid & 3) * 4;        // dword offset: this lane's 4 dims
    for (unsigned pp = quad; pp < nc; pp += 64) {
        const int orig = (int)slots[(size_t)bin * CAP + pp];
        const size_t pb = (size_t)orig * 3;
        const float px = pts[pb], py = pts[pb + 1], pz = pts[pb + 2];

        int   o0[8], o1[8];
        float w0[8], w1[8];
        setup_lds(px * 15.0f, py * 135.0f, pz * 240.0f, 15.0f, 135.0f, 240.0f,
                  x0, y0, z0, L0Y * L0Z * CSTR, L0Z * CSTR, d, o0, w0);
        setup_lds(px * 8.0f, py * 68.0f, pz * 120.0f, 8.0f, 68.0f, 120.0f,
                  x1b, y1b, z1b, L1Y * L1Z * CSTR, L1Z * CSTR, d, o1, w1);

        floatx4 a0 = {0.f, 0.f, 0.f, 0.f}, a1 = {0.f, 0.f, 0.f, 0.f};
#pragma unroll
        for (int c = 0; c < 8; ++c) a0 += w0[c] * *(const floatx4*)(lds0 + o0[c]);
#pragma unroll
        for (int c = 0; c < 8; ++c) a1 += w1[c] * *(const floatx4*)(lds1 + o1[c]);

        // quad writes the 128B row as contiguous 64B chunks per instr
        float* row = out + (size_t)orig * 32 + d;
        __builtin_nontemporal_store(a0, (floatx4*)row);
        __builtin_nontemporal_store(a1, (floatx4*)(row + 16));
    }
}

// ---------------- global-gather setup (overflow + fallback) ----------------
__device__ __forceinline__ void setup_glb(float cx, float cy, float cz,
                                          float tm1, float hm1, float wm1,
                                          int sh, int sw, int d,
                                          int* __restrict__ off,
                                          float* __restrict__ w) {
    float gx[2] = { floorf(cx), floorf(cx + 1.0f) };
    float gy[2] = { floorf(cy), floorf(cy + 1.0f) };
    float gz[2] = { floorf(cz), floorf(cz + 1.0f) };
    float wx[2], wy[2], wz[2];
    int   xo[2], yo[2], zo[2];
#pragma unroll
    for (int b = 0; b < 2; ++b) {
        gx[b] = fminf(fmaxf(gx[b], 0.0f), tm1);
        gy[b] = fminf(fmaxf(gy[b], 0.0f), hm1);
        gz[b] = fminf(fmaxf(gz[b], 0.0f), wm1);
        wx[b] = 1.0f - fabsf(gx[b] - cx);
        wy[b] = 1.0f - fabsf(gy[b] - cy);
        wz[b] = 1.0f - fabsf(gz[b] - cz);
        xo[b] = (int)gx[b] * sh;
        yo[b] = (int)gy[b] * sw;
        zo[b] = (int)gz[b] * 16 + d;
    }
    float wyz[4];
    int   yzo[4];
#pragma unroll
    for (int j = 0; j < 2; ++j)
#pragma unroll
        for (int k = 0; k < 2; ++k) {
            wyz[2 * j + k] = wy[j] * wz[k];
            yzo[2 * j + k] = yo[j] + zo[k];
        }
#pragma unroll
    for (int c = 0; c < 8; ++c) {
        const int i = (c >> 2) & 1, jk = c & 3;
        w[c]   = wx[i] * wyz[jk];
        off[c] = xo[i] + yzo[jk];
    }
}

// overflow: grid-stride over device-side count (empty in practice; outputs
// are bit-identical to the LDS path, so membership nondeterminism is safe:
// same wyz factorization, same accumulation order, same emb values)
__global__ __launch_bounds__(256)
void k_overflow(const unsigned* __restrict__ ovf, const unsigned* __restrict__ ovfc,
                const float* __restrict__ pts,
                const float* __restrict__ emb0, const float* __restrict__ emb1,
                float* __restrict__ out) {
    const unsigned total = *ovfc;
    const int lane4 = (int)(threadIdx.x & 3) * 4;
    for (unsigned i = (blockIdx.x * 256 + threadIdx.x) >> 2; i < total;
         i += (gridDim.x * 256) >> 2) {
        const int p = (int)ovf[i];
        const size_t b = (size_t)p * 3;
        const float px = pts[b], py = pts[b + 1], pz = pts[b + 2];
        int   o0[8], o1[8];
        float w0[8], w1[8];
        setup_glb(px * 15.0f, py * 135.0f, pz * 240.0f, 15.0f, 135.0f, 240.0f,
                  136 * 241 * 16, 241 * 16, lane4, o0, w0);
        setup_glb(px * 8.0f, py * 68.0f, pz * 120.0f, 8.0f, 68.0f, 120.0f,
                  69 * 121 * 16, 121 * 16, lane4, o1, w1);
        floatx4 a0 = {0,0,0,0}, a1 = {0,0,0,0};
#pragma unroll
        for (int c = 0; c < 8; ++c) a0 += w0[c] * *(const floatx4*)(emb0 + o0[c]);
#pragma unroll
        for (int c = 0; c < 8; ++c) a1 += w1[c] * *(const floatx4*)(emb1 + o1[c]);
        float* row = out + (size_t)p * 32 + lane4;
        __builtin_nontemporal_store(a0, (floatx4*)row);
        __builtin_nontemporal_store(a1, (floatx4*)(row + 16));
    }
}

// fallback (ws too small): r6-style direct gathers, 4 lanes/point
__global__ __launch_bounds__(256)
void k_main_plain(const float* __restrict__ pts,
                  const float* __restrict__ emb0,
                  const float* __restrict__ emb1,
                  float* __restrict__ out, int n) {
    const int g = blockIdx.x * blockDim.x + threadIdx.x;
    const int p = g >> 2;
    const int d = (g & 3) * 4;
    if (p >= n) return;
    const size_t b = (size_t)p * 3;
    const float px = pts[b], py = pts[b + 1], pz = pts[b + 2];
    int   o0[8], o1[8];
    float w0[8], w1[8];
    setup_glb(px * 15.0f, py * 135.0f, pz * 240.0f, 15.0f, 135.0f, 240.0f,
              136 * 241 * 16, 241 * 16, d, o0, w0);
    setup_glb(px * 8.0f, py * 68.0f, pz * 120.0f, 8.0f, 68.0f, 120.0f,
              69 * 121 * 16, 121 * 16, d, o1, w1);
    floatx4 a0 = {0,0,0,0}, a1 = {0,0,0,0};
#pragma unroll
    for (int c = 0; c < 8; ++c) a0 += w0[c] * *(const floatx4*)(emb0 + o0[c]);
#pragma unroll
    for (int c = 0; c < 8; ++c) a1 += w1[c] * *(const floatx4*)(emb1 + o1[c]);
    float* row = out + (size_t)p * 32 + d;
    __builtin_nontemporal_store(a0, (floatx4*)row);
    __builtin_nontemporal_store(a1, (floatx4*)(row + 16));
}

extern "C" void kernel_launch(void* const* d_in, const int* in_sizes, int n_in,
                              void* d_out, int out_size, void* d_ws, size_t ws_size,
                              hipStream_t stream) {
    const float* pts  = (const float*)d_in[0];
    const float* emb0 = (const float*)d_in[1];
    const float* emb1 = (const float*)d_in[2];
    float* out = (float*)d_out;
    const int n = in_sizes[0] / 3;

    const int block = 256;
    const int n4      = (n + 3) / 4;
    const int grid_p4 = (n4 + block - 1) / block;
    const int grid_4l = (int)(((long long)n * 4 + block - 1) / block);

    // workspace layout: cnt | ovfc | slots | ovf
    const size_t off_cnt   = 0;
    const size_t off_ovfc  = (size_t)NBINS * 4;
    const size_t off_slots = ((off_ovfc + 4 + 31) & ~(size_t)31);
    const size_t off_ovf   = off_slots + (size_t)NBINS * CAP * 4;
    const size_t need      = off_ovf + (size_t)n * 4;

    if (ws_size < need) {
        k_main_plain<<<grid_4l, block, 0, stream>>>(pts, emb0, emb1, out, n);
        return;
    }

    char* ws = (char*)d_ws;
    unsigned* cnt   = (unsigned*)(ws + off_cnt);
    unsigned* ovfc  = (unsigned*)(ws + off_ovfc);
    unsigned* slots = (unsigned*)(ws + off_slots);
    unsigned* ovf   = (unsigned*)(ws + off_ovf);

    hipMemsetAsync(cnt, 0, off_ovfc + 4, stream);   // cnt + ovfc in one shot
    k_bin<<<grid_p4, block, 0, stream>>>(pts, n, cnt, ovfc, slots, ovf);
    k_main_bins<<<NBINS, block, 0, stream>>>(slots, cnt, pts, emb0, emb1, out);
    k_overflow<<<64, block, 0, stream>>>(ovf, ovfc, pts, emb0, emb1, out);
}

// Round 13
// 118.358 us; speedup vs baseline: 2.6970x; 1.2770x over previous
//
#include <hip/hip_runtime.h>

// MultiHashEncoding: 2-level dense grid trilinear interpolation.
// r12: main 87us (occ 27.6% = 3 blk/CU LDS-capped, VALU 31%, dependent
// slot->pts chain unprefetched), k_bin ~40us (atomic line serialization).
// r13: (1) tightened LDS extents w/ clamped offsets (binade +2 corner has
// weight ~ -1e-7; clamping its LDS offset only -> error ~1e-6 << 8.1e-2):
// L0 3x9x9, L1 3x6x5 => 26.6KB => 6 blk/CU. (2) 4 sub-counter binning
// (different L2 lines -> 4x less atomic serialization). (3) slot/pts
// software prefetch in main loop.
//
// Reference semantics (bit-exact corners): corner = floor(coords + OFFSET)
// with f32 add BEFORE floor; clip to [0,dim-1]; weight from CLIPPED corner.
//
// Extent derivation (key and coords share the same f32 products px*15 /
// py*135 / pz*240, so (int)(px*15) == floor(cx) etc.):
//  L0: floor(cx) in {2bx,2bx+1}; +1-corner <= 2bx+2 (normal) -> x ext 3.
//      floor(cy) in [8by,8by+7] -> y ext 9;  z same -> 9.
//  L1: c1x = px*8 in [1.0667bx, 1.0667(bx+1)) -> floor in {bx,bx+1} -> ext 3.
//      c1y = py*68 in [4.0296by, +4.0296); 544by mod 135 = 4by <= 64 ->
//      floor <= y1b+4 -> ext 6 (y1b = 544by/135 int div).
//      c1z = pz*120 = cz/2 exactly -> floor in [4bz,4bz+3] -> ext 5.
//  Binade +2 corners exceed these by 1 -> LDS offset clamped, weight kept.

typedef float floatx4 __attribute__((ext_vector_type(4)));

#define KXB 8
#define KYB 17
#define KZB 31
#define NBINS (KXB * KYB * KZB)          // 4216
#define NSUB 4
#define CAPS 104                         // per-sub cap: mean 59.3 + 5.8 sigma
#define CAP_TOT (NSUB * CAPS)            // 416

#define L0X 3
#define L0Y 9
#define L0Z 9
#define L0CELLS (L0X * L0Y * L0Z)        // 243
#define L1X 3
#define L1Y 6
#define L1Z 5
#define L1CELLS (L1X * L1Y * L1Z)        // 90
#define CSTR 20                          // 80B cell stride: bank-class spread

__device__ __forceinline__ int point_key(float px, float py, float pz) {
    int ix = (int)(px * 15.0f);  ix = min(max(ix, 0), 15);
    int iy = (int)(py * 135.0f); iy = min(max(iy, 0), 135);
    int iz = (int)(pz * 240.0f); iz = min(max(iz, 0), 240);
    return ((ix >> 1) * KYB + (iy >> 3)) * KZB + (iz >> 3);
}

__device__ __forceinline__ void load4pts(const float* __restrict__ pts, int i4,
                                         float px[4], float py[4], float pz[4]) {
    const floatx4* v = (const floatx4*)(pts + (size_t)i4 * 3);
    const floatx4 a = v[0], b = v[1], c = v[2];
    px[0] = a.x; py[0] = a.y; pz[0] = a.z;
    px[1] = a.w; py[1] = b.x; pz[1] = b.y;
    px[2] = b.z; py[2] = b.w; pz[2] = c.x;
    px[3] = c.y; py[3] = c.z; pz[3] = c.w;
}

// ---------------- single-pass binning, 4 sub-counters ----------------
__global__ __launch_bounds__(256)
void k_bin(const float* __restrict__ pts, int n,
           unsigned* __restrict__ cnt, unsigned* __restrict__ ovfc,
           unsigned* __restrict__ slots, unsigned* __restrict__ ovf) {
    const int i4 = (blockIdx.x * blockDim.x + threadIdx.x) * 4;
    if (i4 >= n) return;
    if (i4 + 3 < n) {
        float px[4], py[4], pz[4];
        load4pts(pts, i4, px, py, pz);
        int k[4];
#pragma unroll
        for (int j = 0; j < 4; ++j) k[j] = point_key(px[j], py[j], pz[j]);
        unsigned pos[4];
#pragma unroll
        for (int j = 0; j < 4; ++j)       // 4 different cnt arrays = 4 L2 lines
            pos[j] = atomicAdd(&cnt[j * NBINS + k[j]], 1u);
#pragma unroll
        for (int j = 0; j < 4; ++j) {
            if (pos[j] < CAPS)
                slots[(size_t)k[j] * CAP_TOT + j * CAPS + pos[j]] = (unsigned)(i4 + j);
            else
                ovf[atomicAdd(ovfc, 1u)] = (unsigned)(i4 + j);
        }
    } else {
        for (int j = 0; j < 4 && i4 + j < n; ++j) {
            const size_t b = (size_t)(i4 + j) * 3;
            const int k = point_key(pts[b], pts[b+1], pts[b+2]);
            const unsigned pos = atomicAdd(&cnt[j * NBINS + k], 1u);
            if (pos < CAPS) slots[(size_t)k * CAP_TOT + j * CAPS + pos] = (unsigned)(i4 + j);
            else            ovf[atomicAdd(ovfc, 1u)] = (unsigned)(i4 + j);
        }
    }
}

// ------- per-level corner setup (LDS dword offsets, clamped extents) -------
__device__ __forceinline__ void setup_lds(float cx, float cy, float cz,
                                          float tm1, float hm1, float wm1,
                                          int xb, int yb, int zb,
                                          int ex, int ey, int ez,   // extent-1
                                          int sx, int sy, int d,
                                          int* __restrict__ off,
                                          float* __restrict__ w) {
    float gx[2] = { floorf(cx), floorf(cx + 1.0f) };
    float gy[2] = { floorf(cy), floorf(cy + 1.0f) };
    float gz[2] = { floorf(cz), floorf(cz + 1.0f) };
    float wx[2], wy[2], wz[2];
    int   xo[2], yo[2], zo[2];
#pragma unroll
    for (int b = 0; b < 2; ++b) {
        gx[b] = fminf(fmaxf(gx[b], 0.0f), tm1);
        gy[b] = fminf(fmaxf(gy[b], 0.0f), hm1);
        gz[b] = fminf(fmaxf(gz[b], 0.0f), wm1);
        wx[b] = 1.0f - fabsf(gx[b] - cx);       // weight from TRUE clipped corner
        wy[b] = 1.0f - fabsf(gy[b] - cy);
        wz[b] = 1.0f - fabsf(gz[b] - cz);
        // LDS offset clamped to staged extent (absorbs ~zero-weight binade +2)
        xo[b] = min((int)gx[b] - xb, ex) * sx;
        yo[b] = min((int)gy[b] - yb, ey) * sy;
        zo[b] = min((int)gz[b] - zb, ez) * CSTR + d;
    }
    float wyz[4];
    int   yzo[4];
#pragma unroll
    for (int j = 0; j < 2; ++j)
#pragma unroll
        for (int k = 0; k < 2; ++k) {
            wyz[2 * j + k] = wy[j] * wz[k];
            yzo[2 * j + k] = yo[j] + zo[k];
        }
#pragma unroll
    for (int c = 0; c < 8; ++c) {
        const int i = (c >> 2) & 1, jk = c & 3;
        w[c]   = wx[i] * wyz[jk];
        off[c] = xo[i] + yzo[jk];
    }
}

// ---------------- main: one block per bin, QUAD per point ----------------
__global__ __launch_bounds__(256)
void k_main_bins(const unsigned* __restrict__ slots,
                 const unsigned* __restrict__ cnt,
                 const float* __restrict__ pts,
                 const float* __restrict__ emb0,
                 const float* __restrict__ emb1,
                 float* __restrict__ out) {
    // bijective XCD swizzle: 4216 = 8 * 527 exactly
    const int bin = (blockIdx.x & 7) * 527 + (blockIdx.x >> 3);
    const unsigned n0 = min(cnt[bin],             (unsigned)CAPS);
    const unsigned n1 = min(cnt[NBINS + bin],     (unsigned)CAPS);
    const unsigned n2 = min(cnt[2 * NBINS + bin], (unsigned)CAPS);
    const unsigned n3 = min(cnt[3 * NBINS + bin], (unsigned)CAPS);
    const unsigned c0 = n0, c1 = c0 + n1, c2 = c1 + n2, nt = c2 + n3;
    if (nt == 0) return;            // uniform branch, before any barrier

    const int bz = bin % KZB;
    const int t1 = bin / KZB;
    const int by = t1 % KYB;
    const int bx = t1 / KYB;

    const int x0 = bx * 2, y0 = by * 8, z0 = bz * 8;
    const int x1b = bx, y1b = (544 * by) / 135, z1b = bz * 4;

    __shared__ float lds0[L0CELLS * CSTR];   // 19.4 KB
    __shared__ float lds1[L1CELLS * CSTR];   //  7.2 KB   (total 26.6 KB -> 6 blk/CU)

    const int tid = threadIdx.x;
    for (int idx = tid; idx < L0CELLS * 4; idx += 256) {
        const int cell = idx >> 2, q = (idx & 3) * 4;
        const int lz = cell % L0Z;
        const int t = cell / L0Z;
        const int ly = t % L0Y, lx = t / L0Y;
        const int gx = min(x0 + lx, 15), gy = min(y0 + ly, 135), gz = min(z0 + lz, 240);
        const floatx4 v = *(const floatx4*)(emb0 + ((size_t)(gx * 136 + gy) * 241 + gz) * 16 + q);
        *(floatx4*)(lds0 + cell * CSTR + q) = v;
    }
    for (int idx = tid; idx < L1CELLS * 4; idx += 256) {
        const int cell = idx >> 2, q = (idx & 3) * 4;
        const int lz = cell % L1Z;
        const int t = cell / L1Z;
        const int ly = t % L1Y, lx = t / L1Y;
        const int gx = min(x1b + lx, 8), gy = min(y1b + ly, 68), gz = min(z1b + lz, 120);
        const floatx4 v = *(const floatx4*)(emb1 + ((size_t)(gx * 69 + gy) * 121 + gz) * 16 + q);
        *(floatx4*)(lds1 + cell * CSTR + q) = v;
    }
    __syncthreads();

    const int quad = tid >> 2;          // 64 quads/block
    const int d = (tid & 3) * 4;        // dword offset: this lane's 4 dims
    const size_t sbase = (size_t)bin * CAP_TOT;

    // linear index t -> slot address over the 4 segments
    auto slot_of = [&](unsigned t) -> unsigned {
        const unsigned seg = (t >= c0) + (t >= c1) + (t >= c2);
        const unsigned base = (seg == 0) ? 0u : ((seg == 1) ? c0 : ((seg == 2) ? c1 : c2));
        return (unsigned)(sbase + seg * CAPS + (t - base));
    };

    // software pipeline: slot 2-ahead, pts 1-ahead
    unsigned tA = quad, tB = quad + 64;
    int origA = (int)slots[slot_of(min(tA, nt - 1))];
    int origB = (int)slots[slot_of(min(tB, nt - 1))];
    size_t pbA = (size_t)origA * 3;
    float pxA = pts[pbA], pyA = pts[pbA + 1], pzA = pts[pbA + 2];

    while (tA < nt) {
        const unsigned tC = tB + 64;
        const int origC = (int)slots[slot_of(min(tC, nt - 1))];
        const size_t pbB = (size_t)origB * 3;
        const float pxB = pts[pbB], pyB = pts[pbB + 1], pzB = pts[pbB + 2];

        int   o0[8], o1[8];
        float w0[8], w1[8];
        setup_lds(pxA * 15.0f, pyA * 135.0f, pzA * 240.0f, 15.0f, 135.0f, 240.0f,
                  x0, y0, z0, L0X - 1, L0Y - 1, L0Z - 1,
                  L0Y * L0Z * CSTR, L0Z * CSTR, d, o0, w0);
        setup_lds(pxA * 8.0f, pyA * 68.0f, pzA * 120.0f, 8.0f, 68.0f, 120.0f,
                  x1b, y1b, z1b, L1X - 1, L1Y - 1, L1Z - 1,
                  L1Y * L1Z * CSTR, L1Z * CSTR, d, o1, w1);

        floatx4 a0 = {0.f, 0.f, 0.f, 0.f}, a1 = {0.f, 0.f, 0.f, 0.f};
#pragma unroll
        for (int c = 0; c < 8; ++c) a0 += w0[c] * *(const floatx4*)(lds0 + o0[c]);
#pragma unroll
        for (int c = 0; c < 8; ++c) a1 += w1[c] * *(const floatx4*)(lds1 + o1[c]);

        // quad writes the 128B row as contiguous 64B chunks per instr
        float* row = out + (size_t)origA * 32 + d;
        __builtin_nontemporal_store(a0, (floatx4*)row);
        __builtin_nontemporal_store(a1, (floatx4*)(row + 16));

        tA = tB; tB = tC;
        origA = origB; origB = origC;
        pxA = pxB; pyA = pyB; pzA = pzB;
    }
}

// ---------------- global-gather setup (overflow + fallback) ----------------
__device__ __forceinline__ void setup_glb(float cx, float cy, float cz,
                                          float tm1, float hm1, float wm1,
                                          int sh, int sw, int d,
                                          int* __restrict__ off,
                                          float* __restrict__ w) {
    float gx[2] = { floorf(cx), floorf(cx + 1.0f) };
    float gy[2] = { floorf(cy), floorf(cy + 1.0f) };
    float gz[2] = { floorf(cz), floorf(cz + 1.0f) };
    float wx[2], wy[2], wz[2];
    int   xo[2], yo[2], zo[2];
#pragma unroll
    for (int b = 0; b < 2; ++b) {
        gx[b] = fminf(fmaxf(gx[b], 0.0f), tm1);
        gy[b] = fminf(fmaxf(gy[b], 0.0f), hm1);
        gz[b] = fminf(fmaxf(gz[b], 0.0f), wm1);
        wx[b] = 1.0f - fabsf(gx[b] - cx);
        wy[b] = 1.0f - fabsf(gy[b] - cy);
        wz[b] = 1.0f - fabsf(gz[b] - cz);
        xo[b] = (int)gx[b] * sh;
        yo[b] = (int)gy[b] * sw;
        zo[b] = (int)gz[b] * 16 + d;
    }
    float wyz[4];
    int   yzo[4];
#pragma unroll
    for (int j = 0; j < 2; ++j)
#pragma unroll
        for (int k = 0; k < 2; ++k) {
            wyz[2 * j + k] = wy[j] * wz[k];
            yzo[2 * j + k] = yo[j] + zo[k];
        }
#pragma unroll
    for (int c = 0; c < 8; ++c) {
        const int i = (c >> 2) & 1, jk = c & 3;
        w[c]   = wx[i] * wyz[jk];
        off[c] = xo[i] + yzo[jk];
    }
}

// overflow: grid-stride over device-side count (empty in practice; outputs
// are bit-identical to the LDS path: same factorization, same order, and
// clamped LDS offsets only differ where weight magnitude ~1e-7)
__global__ __launch_bounds__(256)
void k_overflow(const unsigned* __restrict__ ovf, const unsigned* __restrict__ ovfc,
                const float* __restrict__ pts,
                const float* __restrict__ emb0, const float* __restrict__ emb1,
                float* __restrict__ out) {
    const unsigned total = *ovfc;
    const int lane4 = (int)(threadIdx.x & 3) * 4;
    for (unsigned i = (blockIdx.x * 256 + threadIdx.x) >> 2; i < total;
         i += (gridDim.x * 256) >> 2) {
        const int p = (int)ovf[i];
        const size_t b = (size_t)p * 3;
        const float px = pts[b], py = pts[b + 1], pz = pts[b + 2];
        int   o0[8], o1[8];
        float w0[8], w1[8];
        setup_glb(px * 15.0f, py * 135.0f, pz * 240.0f, 15.0f, 135.0f, 240.0f,
                  136 * 241 * 16, 241 * 16, lane4, o0, w0);
        setup_glb(px * 8.0f, py * 68.0f, pz * 120.0f, 8.0f, 68.0f, 120.0f,
                  69 * 121 * 16, 121 * 16, lane4, o1, w1);
        floatx4 a0 = {0,0,0,0}, a1 = {0,0,0,0};
#pragma unroll
        for (int c = 0; c < 8; ++c) a0 += w0[c] * *(const floatx4*)(emb0 + o0[c]);
#pragma unroll
        for (int c = 0; c < 8; ++c) a1 += w1[c] * *(const floatx4*)(emb1 + o1[c]);
        float* row = out + (size_t)p * 32 + lane4;
        __builtin_nontemporal_store(a0, (floatx4*)row);
        __builtin_nontemporal_store(a1, (floatx4*)(row + 16));
    }
}

// fallback (ws too small): direct gathers, 4 lanes/point
__global__ __launch_bounds__(256)
void k_main_plain(const float* __restrict__ pts,
                  const float* __restrict__ emb0,
                  const float* __restrict__ emb1,
                  float* __restrict__ out, int n) {
    const int g = blockIdx.x * blockDim.x + threadIdx.x;
    const int p = g >> 2;
    const int d = (g & 3) * 4;
    if (p >= n) return;
    const size_t b = (size_t)p * 3;
    const float px = pts[b], py = pts[b + 1], pz = pts[b + 2];
    int   o0[8], o1[8];
    float w0[8], w1[8];
    setup_glb(px * 15.0f, py * 135.0f, pz * 240.0f, 15.0f, 135.0f, 240.0f,
              136 * 241 * 16, 241 * 16, d, o0, w0);
    setup_glb(px * 8.0f, py * 68.0f, pz * 120.0f, 8.0f, 68.0f, 120.0f,
              69 * 121 * 16, 121 * 16, d, o1, w1);
    floatx4 a0 = {0,0,0,0}, a1 = {0,0,0,0};
#pragma unroll
    for (int c = 0; c < 8; ++c) a0 += w0[c] * *(const floatx4*)(emb0 + o0[c]);
#pragma unroll
    for (int c = 0; c < 8; ++c) a1 += w1[c] * *(const floatx4*)(emb1 + o1[c]);
    float* row = out + (size_t)p * 32 + d;
    __builtin_nontemporal_store(a0, (floatx4*)row);
    __builtin_nontemporal_store(a1, (floatx4*)(row + 16));
}

extern "C" void kernel_launch(void* const* d_in, const int* in_sizes, int n_in,
                              void* d_out, int out_size, void* d_ws, size_t ws_size,
                              hipStream_t stream) {
    const float* pts  = (const float*)d_in[0];
    const float* emb0 = (const float*)d_in[1];
    const float* emb1 = (const float*)d_in[2];
    float* out = (float*)d_out;
    const int n = in_sizes[0] / 3;

    const int block = 256;
    const int n4      = (n + 3) / 4;
    const int grid_p4 = (n4 + block - 1) / block;
    const int grid_4l = (int)(((long long)n * 4 + block - 1) / block);

    // workspace layout: cnt[4*NBINS] | ovfc | slots | ovf
    const size_t off_cnt   = 0;
    const size_t off_ovfc  = (size_t)NSUB * NBINS * 4;
    const size_t off_slots = ((off_ovfc + 4 + 31) & ~(size_t)31);
    const size_t off_ovf   = off_slots + (size_t)NBINS * CAP_TOT * 4;
    const size_t need      = off_ovf + (size_t)n * 4;

    if (ws_size < need) {
        k_main_plain<<<grid_4l, block, 0, stream>>>(pts, emb0, emb1, out, n);
        return;
    }

    char* ws = (char*)d_ws;
    unsigned* cnt   = (unsigned*)(ws + off_cnt);
    unsigned* ovfc  = (unsigned*)(ws + off_ovfc);
    unsigned* slots = (unsigned*)(ws + off_slots);
    unsigned* ovf   = (unsigned*)(ws + off_ovf);

    hipMemsetAsync(cnt, 0, off_ovfc + 4, stream);   // cnt + ovfc in one shot
    k_bin<<<grid_p4, block, 0, stream>>>(pts, n, cnt, ovfc, slots, ovf);
    k_main_bins<<<NBINS, block, 0, stream>>>(slots, cnt, pts, emb0, emb1, out);
    k_overflow<<<64, block, 0, stream>>>(ovf, ovfc, pts, emb0, emb1, out);
}

// Round 14
// 115.066 us; speedup vs baseline: 2.7741x; 1.0286x over previous
//
#include <hip/hip_runtime.h>

// MultiHashEncoding: 2-level dense grid trilinear interpolation.
// r13: 118us total; profile polluted by 72us fillBufferAligned (runtime
// memset path). r14: (1) own k_zero kernel (no runtime fill); (2) CSTR
// 20->17: odd stride covers all 32 bank residues (20 covered only 8) and
// shrinks LDS 26.6->22.6KB (7 blk/CU); (3) overflow folded into main.
//
// Reference semantics (bit-exact corners): corner = floor(coords + OFFSET)
// with f32 add BEFORE floor; clip to [0,dim-1]; weight from CLIPPED corner.
//
// Extent derivation (key and coords share the same f32 products px*15 /
// py*135 / pz*240, so (int)(px*15) == floor(cx) etc.):
//  L0: floor(cx) in {2bx,2bx+1}; +1-corner <= 2bx+2 (normal) -> x ext 3.
//      floor(cy) in [8by,8by+7] -> y ext 9;  z same -> 9.
//  L1: c1x = px*8 -> floor in {bx,bx+1} -> ext 3.
//      c1y = py*68; 544by mod 135 = 4by <= 64 -> floor <= y1b+4 -> ext 6.
//      c1z = pz*120 = cz/2 exactly -> floor in [4bz,4bz+3] -> ext 5.
//  Binade +2 corners (weight ~ -1e-7) exceed these by 1 -> LDS offset
//  clamped, weight kept: error ~1e-6 << 8.1e-2 threshold.

typedef float floatx4 __attribute__((ext_vector_type(4)));

#define KXB 8
#define KYB 17
#define KZB 31
#define NBINS (KXB * KYB * KZB)          // 4216
#define NSUB 4
#define CAPS 104                         // per-sub cap: mean 59.3 + 5.8 sigma
#define CAP_TOT (NSUB * CAPS)            // 416
#define CNT_DWORDS (NSUB * NBINS + 1)    // cnt[4*NBINS] + ovfc

#define L0X 3
#define L0Y 9
#define L0Z 9
#define L0CELLS (L0X * L0Y * L0Z)        // 243
#define L1X 3
#define L1Y 6
#define L1Z 5
#define L1CELLS (L1X * L1Y * L1Z)        // 90
#define CSTR 17                          // odd dword stride: all 32 bank residues

__device__ __forceinline__ int point_key(float px, float py, float pz) {
    int ix = (int)(px * 15.0f);  ix = min(max(ix, 0), 15);
    int iy = (int)(py * 135.0f); iy = min(max(iy, 0), 135);
    int iz = (int)(pz * 240.0f); iz = min(max(iz, 0), 240);
    return ((ix >> 1) * KYB + (iy >> 3)) * KZB + (iz >> 3);
}

__device__ __forceinline__ void load4pts(const float* __restrict__ pts, int i4,
                                         float px[4], float py[4], float pz[4]) {
    const floatx4* v = (const floatx4*)(pts + (size_t)i4 * 3);
    const floatx4 a = v[0], b = v[1], c = v[2];
    px[0] = a.x; py[0] = a.y; pz[0] = a.z;
    px[1] = a.w; py[1] = b.x; pz[1] = b.y;
    px[2] = b.z; py[2] = b.w; pz[2] = c.x;
    px[3] = c.y; py[3] = c.z; pz[3] = c.w;
}

// ---------------- pass 0: zero counters (replaces runtime fill) ----------------
__global__ __launch_bounds__(256)
void k_zero(unsigned* __restrict__ cnt) {
    const int i = blockIdx.x * blockDim.x + threadIdx.x;
    if (i < CNT_DWORDS) cnt[i] = 0u;
}

// ---------------- pass 1: single-pass binning, 4 sub-counters ----------------
__global__ __launch_bounds__(256)
void k_bin(const float* __restrict__ pts, int n,
           unsigned* __restrict__ cnt, unsigned* __restrict__ ovfc,
           unsigned* __restrict__ slots, unsigned* __restrict__ ovf) {
    const int i4 = (blockIdx.x * blockDim.x + threadIdx.x) * 4;
    if (i4 >= n) return;
    if (i4 + 3 < n) {
        float px[4], py[4], pz[4];
        load4pts(pts, i4, px, py, pz);
        int k[4];
#pragma unroll
        for (int j = 0; j < 4; ++j) k[j] = point_key(px[j], py[j], pz[j]);
        unsigned pos[4];
#pragma unroll
        for (int j = 0; j < 4; ++j)       // 4 different cnt arrays = 4 L2 lines
            pos[j] = atomicAdd(&cnt[j * NBINS + k[j]], 1u);
#pragma unroll
        for (int j = 0; j < 4; ++j) {
            if (pos[j] < CAPS)
                slots[(size_t)k[j] * CAP_TOT + j * CAPS + pos[j]] = (unsigned)(i4 + j);
            else
                ovf[atomicAdd(ovfc, 1u)] = (unsigned)(i4 + j);
        }
    } else {
        for (int j = 0; j < 4 && i4 + j < n; ++j) {
            const size_t b = (size_t)(i4 + j) * 3;
            const int k = point_key(pts[b], pts[b+1], pts[b+2]);
            const unsigned pos = atomicAdd(&cnt[j * NBINS + k], 1u);
            if (pos < CAPS) slots[(size_t)k * CAP_TOT + j * CAPS + pos] = (unsigned)(i4 + j);
            else            ovf[atomicAdd(ovfc, 1u)] = (unsigned)(i4 + j);
        }
    }
}

// ------- per-level corner setup (LDS dword offsets, clamped extents) -------
__device__ __forceinline__ void setup_lds(float cx, float cy, float cz,
                                          float tm1, float hm1, float wm1,
                                          int xb, int yb, int zb,
                                          int ex, int ey, int ez,   // extent-1
                                          int sx, int sy, int d,
                                          int* __restrict__ off,
                                          float* __restrict__ w) {
    float gx[2] = { floorf(cx), floorf(cx + 1.0f) };
    float gy[2] = { floorf(cy), floorf(cy + 1.0f) };
    float gz[2] = { floorf(cz), floorf(cz + 1.0f) };
    float wx[2], wy[2], wz[2];
    int   xo[2], yo[2], zo[2];
#pragma unroll
    for (int b = 0; b < 2; ++b) {
        gx[b] = fminf(fmaxf(gx[b], 0.0f), tm1);
        gy[b] = fminf(fmaxf(gy[b], 0.0f), hm1);
        gz[b] = fminf(fmaxf(gz[b], 0.0f), wm1);
        wx[b] = 1.0f - fabsf(gx[b] - cx);       // weight from TRUE clipped corner
        wy[b] = 1.0f - fabsf(gy[b] - cy);
        wz[b] = 1.0f - fabsf(gz[b] - cz);
        // LDS offset clamped to staged extent (absorbs ~zero-weight binade +2)
        xo[b] = min((int)gx[b] - xb, ex) * sx;
        yo[b] = min((int)gy[b] - yb, ey) * sy;
        zo[b] = min((int)gz[b] - zb, ez) * CSTR + d;
    }
    float wyz[4];
    int   yzo[4];
#pragma unroll
    for (int j = 0; j < 2; ++j)
#pragma unroll
        for (int k = 0; k < 2; ++k) {
            wyz[2 * j + k] = wy[j] * wz[k];
            yzo[2 * j + k] = yo[j] + zo[k];
        }
#pragma unroll
    for (int c = 0; c < 8; ++c) {
        const int i = (c >> 2) & 1, jk = c & 3;
        w[c]   = wx[i] * wyz[jk];
        off[c] = xo[i] + yzo[jk];
    }
}

// ---------------- global-gather setup (overflow + fallback) ----------------
__device__ __forceinline__ void setup_glb(float cx, float cy, float cz,
                                          float tm1, float hm1, float wm1,
                                          int sh, int sw, int d,
                                          int* __restrict__ off,
                                          float* __restrict__ w) {
    float gx[2] = { floorf(cx), floorf(cx + 1.0f) };
    float gy[2] = { floorf(cy), floorf(cy + 1.0f) };
    float gz[2] = { floorf(cz), floorf(cz + 1.0f) };
    float wx[2], wy[2], wz[2];
    int   xo[2], yo[2], zo[2];
#pragma unroll
    for (int b = 0; b < 2; ++b) {
        gx[b] = fminf(fmaxf(gx[b], 0.0f), tm1);
        gy[b] = fminf(fmaxf(gy[b], 0.0f), hm1);
        gz[b] = fminf(fmaxf(gz[b], 0.0f), wm1);
        wx[b] = 1.0f - fabsf(gx[b] - cx);
        wy[b] = 1.0f - fabsf(gy[b] - cy);
        wz[b] = 1.0f - fabsf(gz[b] - cz);
        xo[b] = (int)gx[b] * sh;
        yo[b] = (int)gy[b] * sw;
        zo[b] = (int)gz[b] * 16 + d;
    }
    float wyz[4];
    int   yzo[4];
#pragma unroll
    for (int j = 0; j < 2; ++j)
#pragma unroll
        for (int k = 0; k < 2; ++k) {
            wyz[2 * j + k] = wy[j] * wz[k];
            yzo[2 * j + k] = yo[j] + zo[k];
        }
#pragma unroll
    for (int c = 0; c < 8; ++c) {
        const int i = (c >> 2) & 1, jk = c & 3;
        w[c]   = wx[i] * wyz[jk];
        off[c] = xo[i] + yzo[jk];
    }
}

__device__ __forceinline__ void encode_glb_quad(int p, int lane4,
                                                const float* __restrict__ pts,
                                                const float* __restrict__ emb0,
                                                const float* __restrict__ emb1,
                                                float* __restrict__ out) {
    const size_t b = (size_t)p * 3;
    const float px = pts[b], py = pts[b + 1], pz = pts[b + 2];
    int   o0[8], o1[8];
    float w0[8], w1[8];
    setup_glb(px * 15.0f, py * 135.0f, pz * 240.0f, 15.0f, 135.0f, 240.0f,
              136 * 241 * 16, 241 * 16, lane4, o0, w0);
    setup_glb(px * 8.0f, py * 68.0f, pz * 120.0f, 8.0f, 68.0f, 120.0f,
              69 * 121 * 16, 121 * 16, lane4, o1, w1);
    floatx4 a0 = {0,0,0,0}, a1 = {0,0,0,0};
#pragma unroll
    for (int c = 0; c < 8; ++c) a0 += w0[c] * *(const floatx4*)(emb0 + o0[c]);
#pragma unroll
    for (int c = 0; c < 8; ++c) a1 += w1[c] * *(const floatx4*)(emb1 + o1[c]);
    float* row = out + (size_t)p * 32 + lane4;
    __builtin_nontemporal_store(a0, (floatx4*)row);
    __builtin_nontemporal_store(a1, (floatx4*)(row + 16));
}

// ------- main: one block per bin, QUAD per point; overflow folded in -------
__global__ __launch_bounds__(256, 6)
void k_main_bins(const unsigned* __restrict__ slots,
                 const unsigned* __restrict__ cnt,
                 const unsigned* __restrict__ ovfc,
                 const unsigned* __restrict__ ovf,
                 const float* __restrict__ pts,
                 const float* __restrict__ emb0,
                 const float* __restrict__ emb1,
                 float* __restrict__ out) {
    // bijective XCD swizzle: 4216 = 8 * 527 exactly
    const int bin = (blockIdx.x & 7) * 527 + (blockIdx.x >> 3);
    const unsigned n0 = min(cnt[bin],             (unsigned)CAPS);
    const unsigned n1 = min(cnt[NBINS + bin],     (unsigned)CAPS);
    const unsigned n2 = min(cnt[2 * NBINS + bin], (unsigned)CAPS);
    const unsigned n3 = min(cnt[3 * NBINS + bin], (unsigned)CAPS);
    const unsigned c0 = n0, c1 = c0 + n1, c2 = c1 + n2, nt = c2 + n3;

    __shared__ float lds0[L0CELLS * CSTR];   // 16.5 KB
    __shared__ float lds1[L1CELLS * CSTR];   //  6.1 KB  (22.6 KB -> 7 blk/CU)

    const int tid = threadIdx.x;
    const int d = (tid & 3) * 4;        // dword offset: this lane's 4 dims

    if (nt != 0) {                      // block-uniform branch: barriers safe
        const int bz = bin % KZB;
        const int t1 = bin / KZB;
        const int by = t1 % KYB;
        const int bx = t1 / KYB;

        const int x0 = bx * 2, y0 = by * 8, z0 = bz * 8;
        const int x1b = bx, y1b = (544 * by) / 135, z1b = bz * 4;

        for (int idx = tid; idx < L0CELLS * 4; idx += 256) {
            const int cell = idx >> 2, q = (idx & 3) * 4;
            const int lz = cell % L0Z;
            const int t = cell / L0Z;
            const int ly = t % L0Y, lx = t / L0Y;
            const int gx = min(x0 + lx, 15), gy = min(y0 + ly, 135), gz = min(z0 + lz, 240);
            const floatx4 v = *(const floatx4*)(emb0 + ((size_t)(gx * 136 + gy) * 241 + gz) * 16 + q);
            *(floatx4*)(lds0 + cell * CSTR + q) = v;
        }
        for (int idx = tid; idx < L1CELLS * 4; idx += 256) {
            const int cell = idx >> 2, q = (idx & 3) * 4;
            const int lz = cell % L1Z;
            const int t = cell / L1Z;
            const int ly = t % L1Y, lx = t / L1Y;
            const int gx = min(x1b + lx, 8), gy = min(y1b + ly, 68), gz = min(z1b + lz, 120);
            const floatx4 v = *(const floatx4*)(emb1 + ((size_t)(gx * 69 + gy) * 121 + gz) * 16 + q);
            *(floatx4*)(lds1 + cell * CSTR + q) = v;
        }
        __syncthreads();

        const int quad = tid >> 2;      // 64 quads/block
        const size_t sbase = (size_t)bin * CAP_TOT;

        auto slot_of = [&](unsigned t) -> unsigned {
            const unsigned seg = (t >= c0) + (t >= c1) + (t >= c2);
            const unsigned base = (seg == 0) ? 0u : ((seg == 1) ? c0 : ((seg == 2) ? c1 : c2));
            return (unsigned)(sbase + seg * CAPS + (t - base));
        };

        // software pipeline: slot 2-ahead, pts 1-ahead
        unsigned tA = quad, tB = quad + 64;
        int origA = (int)slots[slot_of(min(tA, nt - 1))];
        int origB = (int)slots[slot_of(min(tB, nt - 1))];
        size_t pbA = (size_t)origA * 3;
        float pxA = pts[pbA], pyA = pts[pbA + 1], pzA = pts[pbA + 2];

        while (tA < nt) {
            const unsigned tC = tB + 64;
            const int origC = (int)slots[slot_of(min(tC, nt - 1))];
            const size_t pbB = (size_t)origB * 3;
            const float pxB = pts[pbB], pyB = pts[pbB + 1], pzB = pts[pbB + 2];

            int   o0[8], o1[8];
            float w0[8], w1[8];
            setup_lds(pxA * 15.0f, pyA * 135.0f, pzA * 240.0f, 15.0f, 135.0f, 240.0f,
                      x0, y0, z0, L0X - 1, L0Y - 1, L0Z - 1,
                      L0Y * L0Z * CSTR, L0Z * CSTR, d, o0, w0);
            setup_lds(pxA * 8.0f, pyA * 68.0f, pzA * 120.0f, 8.0f, 68.0f, 120.0f,
                      x1b, y1b, z1b, L1X - 1, L1Y - 1, L1Z - 1,
                      L1Y * L1Z * CSTR, L1Z * CSTR, d, o1, w1);

            floatx4 a0 = {0.f, 0.f, 0.f, 0.f}, a1 = {0.f, 0.f, 0.f, 0.f};
#pragma unroll
            for (int c = 0; c < 8; ++c) a0 += w0[c] * *(const floatx4*)(lds0 + o0[c]);
#pragma unroll
            for (int c = 0; c < 8; ++c) a1 += w1[c] * *(const floatx4*)(lds1 + o1[c]);

            // quad writes the 128B row as contiguous 64B chunks per instr
            float* row = out + (size_t)origA * 32 + d;
            __builtin_nontemporal_store(a0, (floatx4*)row);
            __builtin_nontemporal_store(a1, (floatx4*)(row + 16));

            tA = tB; tB = tC;
            origA = origB; origB = origC;
            pxA = pxB; pyA = pyB; pzA = pzB;
        }
    }

    // overflow (folded): first 64 blocks grid-stride the list (empty in
    // practice; outputs bit-identical to LDS path where staged, and the
    // global path is used for ALL corners of an overflow point)
    if (blockIdx.x < 64) {
        const unsigned total = *ovfc;
        for (unsigned i = (blockIdx.x * 256 + tid) >> 2; i < total;
             i += (64u * 256u) >> 2) {
            encode_glb_quad((int)ovf[i], d, pts, emb0, emb1, out);
        }
    }
}

// fallback (ws too small): direct gathers, 4 lanes/point
__global__ __launch_bounds__(256)
void k_main_plain(const float* __restrict__ pts,
                  const float* __restrict__ emb0,
                  const float* __restrict__ emb1,
                  float* __restrict__ out, int n) {
    const int g = blockIdx.x * blockDim.x + threadIdx.x;
    const int p = g >> 2;
    if (p >= n) return;
    encode_glb_quad(p, (g & 3) * 4, pts, emb0, emb1, out);
}

extern "C" void kernel_launch(void* const* d_in, const int* in_sizes, int n_in,
                              void* d_out, int out_size, void* d_ws, size_t ws_size,
                              hipStream_t stream) {
    const float* pts  = (const float*)d_in[0];
    const float* emb0 = (const float*)d_in[1];
    const float* emb1 = (const float*)d_in[2];
    float* out = (float*)d_out;
    const int n = in_sizes[0] / 3;

    const int block = 256;
    const int n4      = (n + 3) / 4;
    const int grid_p4 = (n4 + block - 1) / block;
    const int grid_4l = (int)(((long long)n * 4 + block - 1) / block);
    const int grid_z  = (CNT_DWORDS + block - 1) / block;

    // workspace layout: cnt[4*NBINS] | ovfc | slots | ovf
    const size_t off_cnt   = 0;
    const size_t off_ovfc  = (size_t)NSUB * NBINS * 4;
    const size_t off_slots = ((off_ovfc + 4 + 31) & ~(size_t)31);
    const size_t off_ovf   = off_slots + (size_t)NBINS * CAP_TOT * 4;
    const size_t need      = off_ovf + (size_t)n * 4;

    if (ws_size < need) {
        k_main_plain<<<grid_4l, block, 0, stream>>>(pts, emb0, emb1, out, n);
        return;
    }

    char* ws = (char*)d_ws;
    unsigned* cnt   = (unsigned*)(ws + off_cnt);
    unsigned* ovfc  = (unsigned*)(ws + off_ovfc);
    unsigned* slots = (unsigned*)(ws + off_slots);
    unsigned* ovf   = (unsigned*)(ws + off_ovf);

    k_zero<<<grid_z, block, 0, stream>>>(cnt);   // zeroes cnt + ovfc (contiguous)
    k_bin<<<grid_p4, block, 0, stream>>>(pts, n, cnt, ovfc, slots, ovf);
    k_main_bins<<<NBINS, block, 0, stream>>>(slots, cnt, ovfc, ovf,
                                             pts, emb0, emb1, out);
}

// Round 15
// 114.040 us; speedup vs baseline: 2.7991x; 1.0090x over previous
//
#include <hip/hip_runtime.h>

// MultiHashEncoding: 2-level dense grid trilinear interpolation.
// r14 post-mortem: CSTR=17 broke 16B alignment of LDS lane reads
// ((cell*17+d)*4 % 16 != 0 for odd cells) -> ds_read_b128 split into
// narrow LDS ops -> conflict counter 6.6M->14.9M. r15: CSTR=20 (multiple
// of 4 dwords = aligned b128; 8 bank residues, proven 6.6M regime in r12)
// with r14's tight extents kept: 26.6KB LDS -> 6 blk/CU.
//
// Reference semantics (bit-exact corners): corner = floor(coords + OFFSET)
// with f32 add BEFORE floor; clip to [0,dim-1]; weight from CLIPPED corner.
//
// Extent derivation (key and coords share the same f32 products px*15 /
// py*135 / pz*240, so (int)(px*15) == floor(cx) etc.):
//  L0: floor(cx) in {2bx,2bx+1}; +1-corner <= 2bx+2 (normal) -> x ext 3.
//      floor(cy) in [8by,8by+7] -> y ext 9;  z same -> 9.
//  L1: c1x = px*8 -> floor in {bx,bx+1} -> ext 3.
//      c1y = py*68; 544by mod 135 = 4by <= 64 -> floor <= y1b+4 -> ext 6.
//      c1z = pz*120 = cz/2 exactly -> floor in [4bz,4bz+3] -> ext 5.
//  Binade +2 corners (weight ~ -1e-7) exceed these by 1 -> LDS offset
//  clamped, weight kept: error ~1e-6 << 8.1e-2 threshold.

typedef float floatx4 __attribute__((ext_vector_type(4)));

#define KXB 8
#define KYB 17
#define KZB 31
#define NBINS (KXB * KYB * KZB)          // 4216
#define NSUB 4
#define CAPS 104                         // per-sub cap: mean 59.3 + 5.8 sigma
#define CAP_TOT (NSUB * CAPS)            // 416
#define CNT_DWORDS (NSUB * NBINS + 1)    // cnt[4*NBINS] + ovfc

#define L0X 3
#define L0Y 9
#define L0Z 9
#define L0CELLS (L0X * L0Y * L0Z)        // 243
#define L1X 3
#define L1Y 6
#define L1Z 5
#define L1CELLS (L1X * L1Y * L1Z)        // 90
#define CSTR 20   // dword cell stride: multiple of 4 (16B-aligned b128 reads),
                  // 80B spreads cell bases over all 8 aligned bank residues

__device__ __forceinline__ int point_key(float px, float py, float pz) {
    int ix = (int)(px * 15.0f);  ix = min(max(ix, 0), 15);
    int iy = (int)(py * 135.0f); iy = min(max(iy, 0), 135);
    int iz = (int)(pz * 240.0f); iz = min(max(iz, 0), 240);
    return ((ix >> 1) * KYB + (iy >> 3)) * KZB + (iz >> 3);
}

__device__ __forceinline__ void load4pts(const float* __restrict__ pts, int i4,
                                         float px[4], float py[4], float pz[4]) {
    const floatx4* v = (const floatx4*)(pts + (size_t)i4 * 3);
    const floatx4 a = v[0], b = v[1], c = v[2];
    px[0] = a.x; py[0] = a.y; pz[0] = a.z;
    px[1] = a.w; py[1] = b.x; pz[1] = b.y;
    px[2] = b.z; py[2] = b.w; pz[2] = c.x;
    px[3] = c.y; py[3] = c.z; pz[3] = c.w;
}

// ---------------- pass 0: zero counters ----------------
__global__ __launch_bounds__(256)
void k_zero(unsigned* __restrict__ cnt) {
    const int i = blockIdx.x * blockDim.x + threadIdx.x;
    if (i < CNT_DWORDS) cnt[i] = 0u;
}

// ---------------- pass 1: single-pass binning, 4 sub-counters ----------------
__global__ __launch_bounds__(256)
void k_bin(const float* __restrict__ pts, int n,
           unsigned* __restrict__ cnt, unsigned* __restrict__ ovfc,
           unsigned* __restrict__ slots, unsigned* __restrict__ ovf) {
    const int i4 = (blockIdx.x * blockDim.x + threadIdx.x) * 4;
    if (i4 >= n) return;
    if (i4 + 3 < n) {
        float px[4], py[4], pz[4];
        load4pts(pts, i4, px, py, pz);
        int k[4];
#pragma unroll
        for (int j = 0; j < 4; ++j) k[j] = point_key(px[j], py[j], pz[j]);
        unsigned pos[4];
#pragma unroll
        for (int j = 0; j < 4; ++j)       // 4 different cnt arrays = 4 L2 lines
            pos[j] = atomicAdd(&cnt[j * NBINS + k[j]], 1u);
#pragma unroll
        for (int j = 0; j < 4; ++j) {
            if (pos[j] < CAPS)
                slots[(size_t)k[j] * CAP_TOT + j * CAPS + pos[j]] = (unsigned)(i4 + j);
            else
                ovf[atomicAdd(ovfc, 1u)] = (unsigned)(i4 + j);
        }
    } else {
        for (int j = 0; j < 4 && i4 + j < n; ++j) {
            const size_t b = (size_t)(i4 + j) * 3;
            const int k = point_key(pts[b], pts[b+1], pts[b+2]);
            const unsigned pos = atomicAdd(&cnt[j * NBINS + k], 1u);
            if (pos < CAPS) slots[(size_t)k * CAP_TOT + j * CAPS + pos] = (unsigned)(i4 + j);
            else            ovf[atomicAdd(ovfc, 1u)] = (unsigned)(i4 + j);
        }
    }
}

// ------- per-level corner setup (LDS dword offsets, clamped extents) -------
__device__ __forceinline__ void setup_lds(float cx, float cy, float cz,
                                          float tm1, float hm1, float wm1,
                                          int xb, int yb, int zb,
                                          int ex, int ey, int ez,   // extent-1
                                          int sx, int sy, int d,
                                          int* __restrict__ off,
                                          float* __restrict__ w) {
    float gx[2] = { floorf(cx), floorf(cx + 1.0f) };
    float gy[2] = { floorf(cy), floorf(cy + 1.0f) };
    float gz[2] = { floorf(cz), floorf(cz + 1.0f) };
    float wx[2], wy[2], wz[2];
    int   xo[2], yo[2], zo[2];
#pragma unroll
    for (int b = 0; b < 2; ++b) {
        gx[b] = fminf(fmaxf(gx[b], 0.0f), tm1);
        gy[b] = fminf(fmaxf(gy[b], 0.0f), hm1);
        gz[b] = fminf(fmaxf(gz[b], 0.0f), wm1);
        wx[b] = 1.0f - fabsf(gx[b] - cx);       // weight from TRUE clipped corner
        wy[b] = 1.0f - fabsf(gy[b] - cy);
        wz[b] = 1.0f - fabsf(gz[b] - cz);
        // LDS offset clamped to staged extent (absorbs ~zero-weight binade +2)
        xo[b] = min((int)gx[b] - xb, ex) * sx;
        yo[b] = min((int)gy[b] - yb, ey) * sy;
        zo[b] = min((int)gz[b] - zb, ez) * CSTR + d;
    }
    float wyz[4];
    int   yzo[4];
#pragma unroll
    for (int j = 0; j < 2; ++j)
#pragma unroll
        for (int k = 0; k < 2; ++k) {
            wyz[2 * j + k] = wy[j] * wz[k];
            yzo[2 * j + k] = yo[j] + zo[k];
        }
#pragma unroll
    for (int c = 0; c < 8; ++c) {
        const int i = (c >> 2) & 1, jk = c & 3;
        w[c]   = wx[i] * wyz[jk];
        off[c] = xo[i] + yzo[jk];
    }
}

// ---------------- global-gather setup (overflow + fallback) ----------------
__device__ __forceinline__ void setup_glb(float cx, float cy, float cz,
                                          float tm1, float hm1, float wm1,
                                          int sh, int sw, int d,
                                          int* __restrict__ off,
                                          float* __restrict__ w) {
    float gx[2] = { floorf(cx), floorf(cx + 1.0f) };
    float gy[2] = { floorf(cy), floorf(cy + 1.0f) };
    float gz[2] = { floorf(cz), floorf(cz + 1.0f) };
    float wx[2], wy[2], wz[2];
    int   xo[2], yo[2], zo[2];
#pragma unroll
    for (int b = 0; b < 2; ++b) {
        gx[b] = fminf(fmaxf(gx[b], 0.0f), tm1);
        gy[b] = fminf(fmaxf(gy[b], 0.0f), hm1);
        gz[b] = fminf(fmaxf(gz[b], 0.0f), wm1);
        wx[b] = 1.0f - fabsf(gx[b] - cx);
        wy[b] = 1.0f - fabsf(gy[b] - cy);
        wz[b] = 1.0f - fabsf(gz[b] - cz);
        xo[b] = (int)gx[b] * sh;
        yo[b] = (int)gy[b] * sw;
        zo[b] = (int)gz[b] * 16 + d;
    }
    float wyz[4];
    int   yzo[4];
#pragma unroll
    for (int j = 0; j < 2; ++j)
#pragma unroll
        for (int k = 0; k < 2; ++k) {
            wyz[2 * j + k] = wy[j] * wz[k];
            yzo[2 * j + k] = yo[j] + zo[k];
        }
#pragma unroll
    for (int c = 0; c < 8; ++c) {
        const int i = (c >> 2) & 1, jk = c & 3;
        w[c]   = wx[i] * wyz[jk];
        off[c] = xo[i] + yzo[jk];
    }
}

__device__ __forceinline__ void encode_glb_quad(int p, int lane4,
                                                const float* __restrict__ pts,
                                                const float* __restrict__ emb0,
                                                const float* __restrict__ emb1,
                                                float* __restrict__ out) {
    const size_t b = (size_t)p * 3;
    const float px = pts[b], py = pts[b + 1], pz = pts[b + 2];
    int   o0[8], o1[8];
    float w0[8], w1[8];
    setup_glb(px * 15.0f, py * 135.0f, pz * 240.0f, 15.0f, 135.0f, 240.0f,
              136 * 241 * 16, 241 * 16, lane4, o0, w0);
    setup_glb(px * 8.0f, py * 68.0f, pz * 120.0f, 8.0f, 68.0f, 120.0f,
              69 * 121 * 16, 121 * 16, lane4, o1, w1);
    floatx4 a0 = {0,0,0,0}, a1 = {0,0,0,0};
#pragma unroll
    for (int c = 0; c < 8; ++c) a0 += w0[c] * *(const floatx4*)(emb0 + o0[c]);
#pragma unroll
    for (int c = 0; c < 8; ++c) a1 += w1[c] * *(const floatx4*)(emb1 + o1[c]);
    float* row = out + (size_t)p * 32 + lane4;
    __builtin_nontemporal_store(a0, (floatx4*)row);
    __builtin_nontemporal_store(a1, (floatx4*)(row + 16));
}

// ------- main: one block per bin, QUAD per point; overflow folded in -------
__global__ __launch_bounds__(256, 6)
void k_main_bins(const unsigned* __restrict__ slots,
                 const unsigned* __restrict__ cnt,
                 const unsigned* __restrict__ ovfc,
                 const unsigned* __restrict__ ovf,
                 const float* __restrict__ pts,
                 const float* __restrict__ emb0,
                 const float* __restrict__ emb1,
                 float* __restrict__ out) {
    // bijective XCD swizzle: 4216 = 8 * 527 exactly
    const int bin = (blockIdx.x & 7) * 527 + (blockIdx.x >> 3);
    const unsigned n0 = min(cnt[bin],             (unsigned)CAPS);
    const unsigned n1 = min(cnt[NBINS + bin],     (unsigned)CAPS);
    const unsigned n2 = min(cnt[2 * NBINS + bin], (unsigned)CAPS);
    const unsigned n3 = min(cnt[3 * NBINS + bin], (unsigned)CAPS);
    const unsigned c0 = n0, c1 = c0 + n1, c2 = c1 + n2, nt = c2 + n3;

    __shared__ float lds0[L0CELLS * CSTR];   // 19.4 KB
    __shared__ float lds1[L1CELLS * CSTR];   //  7.2 KB  (26.6 KB -> 6 blk/CU)

    const int tid = threadIdx.x;
    const int d = (tid & 3) * 4;        // dword offset: this lane's 4 dims

    if (nt != 0) {                      // block-uniform branch: barriers safe
        const int bz = bin % KZB;
        const int t1 = bin / KZB;
        const int by = t1 % KYB;
        const int bx = t1 / KYB;

        const int x0 = bx * 2, y0 = by * 8, z0 = bz * 8;
        const int x1b = bx, y1b = (544 * by) / 135, z1b = bz * 4;

        for (int idx = tid; idx < L0CELLS * 4; idx += 256) {
            const int cell = idx >> 2, q = (idx & 3) * 4;
            const int lz = cell % L0Z;
            const int t = cell / L0Z;
            const int ly = t % L0Y, lx = t / L0Y;
            const int gx = min(x0 + lx, 15), gy = min(y0 + ly, 135), gz = min(z0 + lz, 240);
            const floatx4 v = *(const floatx4*)(emb0 + ((size_t)(gx * 136 + gy) * 241 + gz) * 16 + q);
            *(floatx4*)(lds0 + cell * CSTR + q) = v;
        }
        for (int idx = tid; idx < L1CELLS * 4; idx += 256) {
            const int cell = idx >> 2, q = (idx & 3) * 4;
            const int lz = cell % L1Z;
            const int t = cell / L1Z;
            const int ly = t % L1Y, lx = t / L1Y;
            const int gx = min(x1b + lx, 8), gy = min(y1b + ly, 68), gz = min(z1b + lz, 120);
            const floatx4 v = *(const floatx4*)(emb1 + ((size_t)(gx * 69 + gy) * 121 + gz) * 16 + q);
            *(floatx4*)(lds1 + cell * CSTR + q) = v;
        }
        __syncthreads();

        const int quad = tid >> 2;      // 64 quads/block
        const size_t sbase = (size_t)bin * CAP_TOT;

        auto slot_of = [&](unsigned t) -> unsigned {
            const unsigned seg = (t >= c0) + (t >= c1) + (t >= c2);
            const unsigned base = (seg == 0) ? 0u : ((seg == 1) ? c0 : ((seg == 2) ? c1 : c2));
            return (unsigned)(sbase + seg * CAPS + (t - base));
        };

        // software pipeline: slot 2-ahead, pts 1-ahead
        unsigned tA = quad, tB = quad + 64;
        int origA = (int)slots[slot_of(min(tA, nt - 1))];
        int origB = (int)slots[slot_of(min(tB, nt - 1))];
        size_t pbA = (size_t)origA * 3;
        float pxA = pts[pbA], pyA = pts[pbA + 1], pzA = pts[pbA + 2];

        while (tA < nt) {
            const unsigned tC = tB + 64;
            const int origC = (int)slots[slot_of(min(tC, nt - 1))];
            const size_t pbB = (size_t)origB * 3;
            const float pxB = pts[pbB], pyB = pts[pbB + 1], pzB = pts[pbB + 2];

            int   o0[8], o1[8];
            float w0[8], w1[8];
            setup_lds(pxA * 15.0f, pyA * 135.0f, pzA * 240.0f, 15.0f, 135.0f, 240.0f,
                      x0, y0, z0, L0X - 1, L0Y - 1, L0Z - 1,
                      L0Y * L0Z * CSTR, L0Z * CSTR, d, o0, w0);
            setup_lds(pxA * 8.0f, pyA * 68.0f, pzA * 120.0f, 8.0f, 68.0f, 120.0f,
                      x1b, y1b, z1b, L1X - 1, L1Y - 1, L1Z - 1,
                      L1Y * L1Z * CSTR, L1Z * CSTR, d, o1, w1);

            floatx4 a0 = {0.f, 0.f, 0.f, 0.f}, a1 = {0.f, 0.f, 0.f, 0.f};
#pragma unroll
            for (int c = 0; c < 8; ++c) a0 += w0[c] * *(const floatx4*)(lds0 + o0[c]);
#pragma unroll
            for (int c = 0; c < 8; ++c) a1 += w1[c] * *(const floatx4*)(lds1 + o1[c]);

            // quad writes the 128B row as contiguous 64B chunks per instr
            float* row = out + (size_t)origA * 32 + d;
            __builtin_nontemporal_store(a0, (floatx4*)row);
            __builtin_nontemporal_store(a1, (floatx4*)(row + 16));

            tA = tB; tB = tC;
            origA = origB; origB = origC;
            pxA = pxB; pyA = pyB; pzA = pzB;
        }
    }

    // overflow (folded): first 64 blocks grid-stride the list (empty in
    // practice; the global path is used for ALL corners of an overflow point)
    if (blockIdx.x < 64) {
        const unsigned total = *ovfc;
        for (unsigned i = (blockIdx.x * 256 + tid) >> 2; i < total;
             i += (64u * 256u) >> 2) {
            encode_glb_quad((int)ovf[i], d, pts, emb0, emb1, out);
        }
    }
}

// fallback (ws too small): direct gathers, 4 lanes/point
__global__ __launch_bounds__(256)
void k_main_plain(const float* __restrict__ pts,
                  const float* __restrict__ emb0,
                  const float* __restrict__ emb1,
                  float* __restrict__ out, int n) {
    const int g = blockIdx.x * blockDim.x + threadIdx.x;
    const int p = g >> 2;
    if (p >= n) return;
    encode_glb_quad(p, (g & 3) * 4, pts, emb0, emb1, out);
}

extern "C" void kernel_launch(void* const* d_in, const int* in_sizes, int n_in,
                              void* d_out, int out_size, void* d_ws, size_t ws_size,
                              hipStream_t stream) {
    const float* pts  = (const float*)d_in[0];
    const float* emb0 = (const float*)d_in[1];
    const float* emb1 = (const float*)d_in[2];
    float* out = (float*)d_out;
    const int n = in_sizes[0] / 3;

    const int block = 256;
    const int n4      = (n + 3) / 4;
    const int grid_p4 = (n4 + block - 1) / block;
    const int grid_4l = (int)(((long long)n * 4 + block - 1) / block);
    const int grid_z  = (CNT_DWORDS + block - 1) / block;

    // workspace layout: cnt[4*NBINS] | ovfc | slots | ovf
    const size_t off_cnt   = 0;
    const size_t off_ovfc  = (size_t)NSUB * NBINS * 4;
    const size_t off_slots = ((off_ovfc + 4 + 31) & ~(size_t)31);
    const size_t off_ovf   = off_slots + (size_t)NBINS * CAP_TOT * 4;
    const size_t need      = off_ovf + (size_t)n * 4;

    if (ws_size < need) {
        k_main_plain<<<grid_4l, block, 0, stream>>>(pts, emb0, emb1, out, n);
        return;
    }

    char* ws = (char*)d_ws;
    unsigned* cnt   = (unsigned*)(ws + off_cnt);
    unsigned* ovfc  = (unsigned*)(ws + off_ovfc);
    unsigned* slots = (unsigned*)(ws + off_slots);
    unsigned* ovf   = (unsigned*)(ws + off_ovf);

    k_zero<<<grid_z, block, 0, stream>>>(cnt);   // zeroes cnt + ovfc (contiguous)
    k_bin<<<grid_p4, block, 0, stream>>>(pts, n, cnt, ovfc, slots, ovf);
    k_main_bins<<<NBINS, block, 0, stream>>>(slots, cnt, ovfc, ovf,
                                             pts, emb0, emb1, out);
}

// Round 16
// 111.262 us; speedup vs baseline: 2.8690x; 1.0250x over previous
//
#include <hip/hip_runtime.h>

// MultiHashEncoding: 2-level dense grid trilinear interpolation.
// r15 budget: main's LDS pipe (16 ds_read_b128/pt ~20us + ~10us conflicts)
// dominates. emb1 = 4.8MB -> per-XCD slice ~0.6MB = L2-resident. r16: drop
// L1 staging; L1 gathers go straight to L2 (8x 64B txns/pt, issued before
// the L0 LDS accumulate). LDS reads/pt 16->8, conflicts halve, LDS 26.6->
// 19.4KB, L1 path becomes bit-exact (no extent clamp).
//
// Reference semantics (bit-exact corners): corner = floor(coords + OFFSET)
// with f32 add BEFORE floor; clip to [0,dim-1]; weight from CLIPPED corner.
//
// L0 extent derivation (key and coords share the same f32 product px*15 etc,
// so (int)(px*15) == floor(cx)): floor(cx) in {2bx,2bx+1} -> x ext 3;
// floor(cy) in [8by,8by+7] -> y ext 9; z same -> 9. Binade +2 corners
// (weight ~ -1e-7) exceed by 1 -> LDS offset clamped, weight kept (err ~1e-6).

typedef float floatx4 __attribute__((ext_vector_type(4)));

#define KXB 8
#define KYB 17
#define KZB 31
#define NBINS (KXB * KYB * KZB)          // 4216
#define NSUB 4
#define CAPS 104                         // per-sub cap: mean 59.3 + 5.8 sigma
#define CAP_TOT (NSUB * CAPS)            // 416
#define CNT_DWORDS (NSUB * NBINS + 1)    // cnt[4*NBINS] + ovfc

#define L0X 3
#define L0Y 9
#define L0Z 9
#define L0CELLS (L0X * L0Y * L0Z)        // 243
#define CSTR 20   // dword cell stride: multiple of 4 (16B-aligned b128 reads),
                  // 80B spreads cell bases over all 8 aligned bank residues

__device__ __forceinline__ int point_key(float px, float py, float pz) {
    int ix = (int)(px * 15.0f);  ix = min(max(ix, 0), 15);
    int iy = (int)(py * 135.0f); iy = min(max(iy, 0), 135);
    int iz = (int)(pz * 240.0f); iz = min(max(iz, 0), 240);
    return ((ix >> 1) * KYB + (iy >> 3)) * KZB + (iz >> 3);
}

__device__ __forceinline__ void load4pts(const float* __restrict__ pts, int i4,
                                         float px[4], float py[4], float pz[4]) {
    const floatx4* v = (const floatx4*)(pts + (size_t)i4 * 3);
    const floatx4 a = v[0], b = v[1], c = v[2];
    px[0] = a.x; py[0] = a.y; pz[0] = a.z;
    px[1] = a.w; py[1] = b.x; pz[1] = b.y;
    px[2] = b.z; py[2] = b.w; pz[2] = c.x;
    px[3] = c.y; py[3] = c.z; pz[3] = c.w;
}

// ---------------- pass 0: zero counters ----------------
__global__ __launch_bounds__(256)
void k_zero(unsigned* __restrict__ cnt) {
    const int i = blockIdx.x * blockDim.x + threadIdx.x;
    if (i < CNT_DWORDS) cnt[i] = 0u;
}

// ---------------- pass 1: single-pass binning, 4 sub-counters ----------------
__global__ __launch_bounds__(256)
void k_bin(const float* __restrict__ pts, int n,
           unsigned* __restrict__ cnt, unsigned* __restrict__ ovfc,
           unsigned* __restrict__ slots, unsigned* __restrict__ ovf) {
    const int i4 = (blockIdx.x * blockDim.x + threadIdx.x) * 4;
    if (i4 >= n) return;
    if (i4 + 3 < n) {
        float px[4], py[4], pz[4];
        load4pts(pts, i4, px, py, pz);
        int k[4];
#pragma unroll
        for (int j = 0; j < 4; ++j) k[j] = point_key(px[j], py[j], pz[j]);
        unsigned pos[4];
#pragma unroll
        for (int j = 0; j < 4; ++j)       // 4 different cnt arrays = 4 L2 lines
            pos[j] = atomicAdd(&cnt[j * NBINS + k[j]], 1u);
#pragma unroll
        for (int j = 0; j < 4; ++j) {
            if (pos[j] < CAPS)
                slots[(size_t)k[j] * CAP_TOT + j * CAPS + pos[j]] = (unsigned)(i4 + j);
            else
                ovf[atomicAdd(ovfc, 1u)] = (unsigned)(i4 + j);
        }
    } else {
        for (int j = 0; j < 4 && i4 + j < n; ++j) {
            const size_t b = (size_t)(i4 + j) * 3;
            const int k = point_key(pts[b], pts[b+1], pts[b+2]);
            const unsigned pos = atomicAdd(&cnt[j * NBINS + k], 1u);
            if (pos < CAPS) slots[(size_t)k * CAP_TOT + j * CAPS + pos] = (unsigned)(i4 + j);
            else            ovf[atomicAdd(ovfc, 1u)] = (unsigned)(i4 + j);
        }
    }
}

// ------- L0 corner setup (LDS dword offsets, clamped extents) -------
__device__ __forceinline__ void setup_lds(float cx, float cy, float cz,
                                          int xb, int yb, int zb, int d,
                                          int* __restrict__ off,
                                          float* __restrict__ w) {
    float gx[2] = { floorf(cx), floorf(cx + 1.0f) };
    float gy[2] = { floorf(cy), floorf(cy + 1.0f) };
    float gz[2] = { floorf(cz), floorf(cz + 1.0f) };
    float wx[2], wy[2], wz[2];
    int   xo[2], yo[2], zo[2];
#pragma unroll
    for (int b = 0; b < 2; ++b) {
        gx[b] = fminf(fmaxf(gx[b], 0.0f), 15.0f);
        gy[b] = fminf(fmaxf(gy[b], 0.0f), 135.0f);
        gz[b] = fminf(fmaxf(gz[b], 0.0f), 240.0f);
        wx[b] = 1.0f - fabsf(gx[b] - cx);       // weight from TRUE clipped corner
        wy[b] = 1.0f - fabsf(gy[b] - cy);
        wz[b] = 1.0f - fabsf(gz[b] - cz);
        // LDS offset clamped to staged extent (absorbs ~zero-weight binade +2)
        xo[b] = min((int)gx[b] - xb, L0X - 1) * (L0Y * L0Z * CSTR);
        yo[b] = min((int)gy[b] - yb, L0Y - 1) * (L0Z * CSTR);
        zo[b] = min((int)gz[b] - zb, L0Z - 1) * CSTR + d;
    }
    float wyz[4];
    int   yzo[4];
#pragma unroll
    for (int j = 0; j < 2; ++j)
#pragma unroll
        for (int k = 0; k < 2; ++k) {
            wyz[2 * j + k] = wy[j] * wz[k];
            yzo[2 * j + k] = yo[j] + zo[k];
        }
#pragma unroll
    for (int c = 0; c < 8; ++c) {
        const int i = (c >> 2) & 1, jk = c & 3;
        w[c]   = wx[i] * wyz[jk];
        off[c] = xo[i] + yzo[jk];
    }
}

// ---------------- global-gather setup (L1 + overflow + fallback) ------------
__device__ __forceinline__ void setup_glb(float cx, float cy, float cz,
                                          float tm1, float hm1, float wm1,
                                          int sh, int sw, int d,
                                          int* __restrict__ off,
                                          float* __restrict__ w) {
    float gx[2] = { floorf(cx), floorf(cx + 1.0f) };
    float gy[2] = { floorf(cy), floorf(cy + 1.0f) };
    float gz[2] = { floorf(cz), floorf(cz + 1.0f) };
    float wx[2], wy[2], wz[2];
    int   xo[2], yo[2], zo[2];
#pragma unroll
    for (int b = 0; b < 2; ++b) {
        gx[b] = fminf(fmaxf(gx[b], 0.0f), tm1);
        gy[b] = fminf(fmaxf(gy[b], 0.0f), hm1);
        gz[b] = fminf(fmaxf(gz[b], 0.0f), wm1);
        wx[b] = 1.0f - fabsf(gx[b] - cx);
        wy[b] = 1.0f - fabsf(gy[b] - cy);
        wz[b] = 1.0f - fabsf(gz[b] - cz);
        xo[b] = (int)gx[b] * sh;
        yo[b] = (int)gy[b] * sw;
        zo[b] = (int)gz[b] * 16 + d;
    }
    float wyz[4];
    int   yzo[4];
#pragma unroll
    for (int j = 0; j < 2; ++j)
#pragma unroll
        for (int k = 0; k < 2; ++k) {
            wyz[2 * j + k] = wy[j] * wz[k];
            yzo[2 * j + k] = yo[j] + zo[k];
        }
#pragma unroll
    for (int c = 0; c < 8; ++c) {
        const int i = (c >> 2) & 1, jk = c & 3;
        w[c]   = wx[i] * wyz[jk];
        off[c] = xo[i] + yzo[jk];
    }
}

__device__ __forceinline__ void encode_glb_quad(int p, int lane4,
                                                const float* __restrict__ pts,
                                                const float* __restrict__ emb0,
                                                const float* __restrict__ emb1,
                                                float* __restrict__ out) {
    const size_t b = (size_t)p * 3;
    const float px = pts[b], py = pts[b + 1], pz = pts[b + 2];
    int   o0[8], o1[8];
    float w0[8], w1[8];
    setup_glb(px * 15.0f, py * 135.0f, pz * 240.0f, 15.0f, 135.0f, 240.0f,
              136 * 241 * 16, 241 * 16, lane4, o0, w0);
    setup_glb(px * 8.0f, py * 68.0f, pz * 120.0f, 8.0f, 68.0f, 120.0f,
              69 * 121 * 16, 121 * 16, lane4, o1, w1);
    floatx4 a0 = {0,0,0,0}, a1 = {0,0,0,0};
#pragma unroll
    for (int c = 0; c < 8; ++c) a0 += w0[c] * *(const floatx4*)(emb0 + o0[c]);
#pragma unroll
    for (int c = 0; c < 8; ++c) a1 += w1[c] * *(const floatx4*)(emb1 + o1[c]);
    float* row = out + (size_t)p * 32 + lane4;
    __builtin_nontemporal_store(a0, (floatx4*)row);
    __builtin_nontemporal_store(a1, (floatx4*)(row + 16));
}

// ------- main: one block per bin, QUAD per point; L0 from LDS, L1 from L2 ---
__global__ __launch_bounds__(256, 4)
void k_main_bins(const unsigned* __restrict__ slots,
                 const unsigned* __restrict__ cnt,
                 const unsigned* __restrict__ ovfc,
                 const unsigned* __restrict__ ovf,
                 const float* __restrict__ pts,
                 const float* __restrict__ emb0,
                 const float* __restrict__ emb1,
                 float* __restrict__ out) {
    // bijective XCD swizzle: 4216 = 8 * 527 exactly
    const int bin = (blockIdx.x & 7) * 527 + (blockIdx.x >> 3);
    const unsigned n0 = min(cnt[bin],             (unsigned)CAPS);
    const unsigned n1 = min(cnt[NBINS + bin],     (unsigned)CAPS);
    const unsigned n2 = min(cnt[2 * NBINS + bin], (unsigned)CAPS);
    const unsigned n3 = min(cnt[3 * NBINS + bin], (unsigned)CAPS);
    const unsigned c0 = n0, c1 = c0 + n1, c2 = c1 + n2, nt = c2 + n3;

    __shared__ float lds0[L0CELLS * CSTR];   // 19.4 KB (L1 not staged)

    const int tid = threadIdx.x;
    const int d = (tid & 3) * 4;        // dword offset: this lane's 4 dims

    if (nt != 0) {                      // block-uniform branch: barriers safe
        const int bz = bin % KZB;
        const int t1 = bin / KZB;
        const int by = t1 % KYB;
        const int bx = t1 / KYB;

        const int x0 = bx * 2, y0 = by * 8, z0 = bz * 8;

        for (int idx = tid; idx < L0CELLS * 4; idx += 256) {
            const int cell = idx >> 2, q = (idx & 3) * 4;
            const int lz = cell % L0Z;
            const int t = cell / L0Z;
            const int ly = t % L0Y, lx = t / L0Y;
            const int gx = min(x0 + lx, 15), gy = min(y0 + ly, 135), gz = min(z0 + lz, 240);
            const floatx4 v = *(const floatx4*)(emb0 + ((size_t)(gx * 136 + gy) * 241 + gz) * 16 + q);
            *(floatx4*)(lds0 + cell * CSTR + q) = v;
        }
        __syncthreads();

        const int quad = tid >> 2;      // 64 quads/block
        const size_t sbase = (size_t)bin * CAP_TOT;

        auto slot_of = [&](unsigned t) -> unsigned {
            const unsigned seg = (t >= c0) + (t >= c1) + (t >= c2);
            const unsigned base = (seg == 0) ? 0u : ((seg == 1) ? c0 : ((seg == 2) ? c1 : c2));
            return (unsigned)(sbase + seg * CAPS + (t - base));
        };

        // software pipeline: slot 2-ahead, pts 1-ahead
        unsigned tA = quad, tB = quad + 64;
        int origA = (int)slots[slot_of(min(tA, nt - 1))];
        int origB = (int)slots[slot_of(min(tB, nt - 1))];
        size_t pbA = (size_t)origA * 3;
        float pxA = pts[pbA], pyA = pts[pbA + 1], pzA = pts[pbA + 2];

        while (tA < nt) {
            const unsigned tC = tB + 64;
            const int origC = (int)slots[slot_of(min(tC, nt - 1))];
            const size_t pbB = (size_t)origB * 3;
            const float pxB = pts[pbB], pyB = pts[pbB + 1], pzB = pts[pbB + 2];

            int   o0[8], o1[8];
            float w0[8], w1[8];
            setup_lds(pxA * 15.0f, pyA * 135.0f, pzA * 240.0f, x0, y0, z0, d, o0, w0);
            // L1 direct (bit-exact, no clamp): global dword offsets
            setup_glb(pxA * 8.0f, pyA * 68.0f, pzA * 120.0f, 8.0f, 68.0f, 120.0f,
                      69 * 121 * 16, 121 * 16, d, o1, w1);

            // issue all 8 L1 gathers (L2-resident: per-XCD emb1 slice ~0.6MB),
            // pin them before the L0 LDS work so they stay in flight under it
            floatx4 v1[8];
#pragma unroll
            for (int c = 0; c < 8; ++c) v1[c] = *(const floatx4*)(emb1 + o1[c]);
            __builtin_amdgcn_sched_barrier(0);

            floatx4 a0 = {0.f, 0.f, 0.f, 0.f}, a1 = {0.f, 0.f, 0.f, 0.f};
#pragma unroll
            for (int c = 0; c < 8; ++c) a0 += w0[c] * *(const floatx4*)(lds0 + o0[c]);
#pragma unroll
            for (int c = 0; c < 8; ++c) a1 += w1[c] * v1[c];

            // quad writes the 128B row as contiguous 64B chunks per instr
            float* row = out + (size_t)origA * 32 + d;
            __builtin_nontemporal_store(a0, (floatx4*)row);
            __builtin_nontemporal_store(a1, (floatx4*)(row + 16));

            tA = tB; tB = tC;
            origA = origB; origB = origC;
            pxA = pxB; pyA = pyB; pzA = pzB;
        }
    }

    // overflow (folded): first 64 blocks grid-stride the list (empty in
    // practice; the global path is used for ALL corners of an overflow point)
    if (blockIdx.x < 64) {
        const unsigned total = *ovfc;
        for (unsigned i = (blockIdx.x * 256 + tid) >> 2; i < total;
             i += (64u * 256u) >> 2) {
            encode_glb_quad((int)ovf[i], d, pts, emb0, emb1, out);
        }
    }
}

// fallback (ws too small): direct gathers, 4 lanes/point
__global__ __launch_bounds__(256)
void k_main_plain(const float* __restrict__ pts,
                  const float* __restrict__ emb0,
                  const float* __restrict__ emb1,
                  float* __restrict__ out, int n) {
    const int g = blockIdx.x * blockDim.x + threadIdx.x;
    const int p = g >> 2;
    if (p >= n) return;
    encode_glb_quad(p, (g & 3) * 4, pts, emb0, emb1, out);
}

extern "C" void kernel_launch(void* const* d_in, const int* in_sizes, int n_in,
                              void* d_out, int out_size, void* d_ws, size_t ws_size,
                              hipStream_t stream) {
    const float* pts  = (const float*)d_in[0];
    const float* emb0 = (const float*)d_in[1];
    const float* emb1 = (const float*)d_in[2];
    float* out = (float*)d_out;
    const int n = in_sizes[0] / 3;

    const int block = 256;
    const int n4      = (n + 3) / 4;
    const int grid_p4 = (n4 + block - 1) / block;
    const int grid_4l = (int)(((long long)n * 4 + block - 1) / block);
    const int grid_z  = (CNT_DWORDS + block - 1) / block;

    // workspace layout: cnt[4*NBINS] | ovfc | slots | ovf
    const size_t off_cnt   = 0;
    const size_t off_ovfc  = (size_t)NSUB * NBINS * 4;
    const size_t off_slots = ((off_ovfc + 4 + 31) & ~(size_t)31);
    const size_t off_ovf   = off_slots + (size_t)NBINS * CAP_TOT * 4;
    const size_t need      = off_ovf + (size_t)n * 4;

    if (ws_size < need) {
        k_main_plain<<<grid_4l, block, 0, stream>>>(pts, emb0, emb1, out, n);
        return;
    }

    char* ws = (char*)d_ws;
    unsigned* cnt   = (unsigned*)(ws + off_cnt);
    unsigned* ovfc  = (unsigned*)(ws + off_ovfc);
    unsigned* slots = (unsigned*)(ws + off_slots);
    unsigned* ovf   = (unsigned*)(ws + off_ovf);

    k_zero<<<grid_z, block, 0, stream>>>(cnt);   // zeroes cnt + ovfc (contiguous)
    k_bin<<<grid_p4, block, 0, stream>>>(pts, n, cnt, ovfc, slots, ovf);
    k_main_bins<<<NBINS, block, 0, stream>>>(slots, cnt, ovfc, ovf,
                                             pts, emb0, emb1, out);
}